// Round 12
// baseline (185.294 us; speedup 1.0000x reference)
//
#include <hip/hip_runtime.h>

#define S_LEN 2048
#define D_MODEL 512

typedef __attribute__((ext_vector_type(8))) short s8v;   // 8 x bf16 (4 VGPRs) MFMA A/B frag
typedef __attribute__((ext_vector_type(4))) float f4v;   // MFMA C/D frag
typedef __attribute__((ext_vector_type(4))) short s4v;
typedef __attribute__((ext_vector_type(4))) int   i4v;
typedef __attribute__((ext_vector_type(2))) int   i2v;

#define MFMA __builtin_amdgcn_mfma_f32_16x16x32_bf16

__device__ inline short f2bf(float x) {            // fp32 -> bf16 RNE
    union { float f; unsigned u; } v; v.f = x;
    unsigned r = v.u + 0x7fffu + ((v.u >> 16) & 1u);
    return (short)(r >> 16);
}
__device__ inline unsigned pack_bf2_trunc(float a, float b) { // truncating pack: 3 inst
    unsigned ua = __builtin_bit_cast(unsigned, a);
    unsigned ub = __builtin_bit_cast(unsigned, b);
    return (ua >> 16) | (ub & 0xffff0000u);
}

template <int C>
__device__ inline float dppf(float x) {            // DPP permute within 16-lane row
    int i = __builtin_bit_cast(int, x);
    i = __builtin_amdgcn_update_dpp(0, i, C, 0xF, 0xF, true);
    return __builtin_bit_cast(float, i);
}
__device__ inline float rowsum16(float x) {
    x += dppf<0xB1>(x);
    x += dppf<0x4E>(x);
    x += dppf<0x141>(x);
    x += dppf<0x140>(x);
    return x;
}

// ---------------- fused projections+repack+Wo-prep ------------------------------------
// z<12: projections. Each block covers 128 rows = exactly two 64-key frag tiles,
// so K/V frag reordering happens in-block: acc -> LDS (s,e) tile -> frag-order
// gather -> coalesced 1KB stores. LDS XOR swizzle keyed ((row>>2)&7), write+read.
// z==12: the Wo->WoT bf16 transpose rides in this grid (64 active blocks, reusing
// sm as the transpose tile) -> one fewer kernel launch; runs concurrent with proj.
__global__ __launch_bounds__(256) void proj_kernel(
    const float* __restrict__ q, const float* __restrict__ k, const float* __restrict__ v,
    const float* __restrict__ Wq, const float* __restrict__ Wk, const float* __restrict__ Wv,
    const float* __restrict__ bq, const float* __restrict__ bk, const float* __restrict__ bv,
    const float* __restrict__ Wo, short* __restrict__ WoT,
    short* __restrict__ qp, short* __restrict__ kfrag, short* __restrict__ vfrag)
{
    __shared__ short sm[128 * 64];     // 16 KB union: wsm/ksm/vsm, or prep tile (z==12)

    if (blockIdx.z == 12) {            // ---- Wo transpose slice ----
        const int idx = blockIdx.y * 16 + blockIdx.x;   // 0..127, need 64
        if (idx >= 64) return;
        const int bi = (idx >> 3) * 64;   // input-dim base (i)
        const int bj = (idx & 7) * 64;    // output-dim base (o)
        const int c = threadIdx.x & 63, rr = threadIdx.x >> 6;
        short* t = sm;                    // 64*65 shorts <= sm
#pragma unroll
        for (int r = 0; r < 16; r++) {
            int i = r * 4 + rr;
            t[c * 65 + i] = f2bf(Wo[(size_t)(bi + i) * 512 + bj + c]);  // coalesced read
        }
        __syncthreads();
#pragma unroll
        for (int r = 0; r < 16; r++) {
            int o = r * 4 + rr;
            WoT[(size_t)(bj + o) * 512 + bi + c] = t[o * 65 + c];       // coalesced write
        }
        return;
    }

    const int t = blockIdx.z >> 2;     // 0:q 1:k 2:v
    const int b = blockIdx.z & 3;
    const int h = blockIdx.y;
    const int qt = blockIdx.x;         // 16 row-tiles of 128
    const int w = threadIdx.x >> 6, lane = threadIdx.x & 63;
    const int l = lane & 15, qd = lane >> 4;

    const float* X    = (t == 0) ? q  : (t == 1) ? k  : v;
    const float* Wp   = (t == 0) ? Wq : (t == 1) ? Wk : Wv;
    const float* bias = (t == 0) ? bq : (t == 1) ? bk : bv;

    // ---- stage wsm[e][d] = W[d][e] (bf16, row-swizzled) ----
    {
        const int d = threadIdx.x >> 2, c4 = threadIdx.x & 3;   // 16 cols per thread
        const float* src = Wp + d * 64 + c4 * 16;
        f4v x0 = *(const f4v*)(src);
        f4v x1 = *(const f4v*)(src + 4);
        f4v x2 = *(const f4v*)(src + 8);
        f4v x3 = *(const f4v*)(src + 12);
        float xs[16] = {x0[0],x0[1],x0[2],x0[3], x1[0],x1[1],x1[2],x1[3],
                        x2[0],x2[1],x2[2],x2[3], x3[0],x3[1],x3[2],x3[3]};
#pragma unroll
        for (int j = 0; j < 16; j++) {
            int e = c4 * 16 + j;
            int sidx = (e * 64 + d) ^ (((e >> 2) & 7) << 3);
            sm[sidx] = f2bf(xs[j]);
        }
    }
    __syncthreads();

    const int s0 = qt * 128 + w * 32;

    // A frags direct from global fp32, converted
    s8v a[2][2];
#pragma unroll
    for (int mt = 0; mt < 2; mt++)
#pragma unroll
        for (int kk = 0; kk < 2; kk++) {
            const float* p = X + (size_t)(b * S_LEN + s0 + mt * 16 + l) * 512 + h * 64 + kk * 32 + qd * 8;
            f4v x0 = *(const f4v*)p;
            f4v x1 = *(const f4v*)(p + 4);
            s8v fr;
            fr[0] = f2bf(x0[0]); fr[1] = f2bf(x0[1]); fr[2] = f2bf(x0[2]); fr[3] = f2bf(x0[3]);
            fr[4] = f2bf(x1[0]); fr[5] = f2bf(x1[1]); fr[6] = f2bf(x1[2]); fr[7] = f2bf(x1[3]);
            a[mt][kk] = fr;
        }
    // B frags from wsm: q/k use e = 4*l + nt, v uses e = nt*16 + l
    s8v wf[4][2];
#pragma unroll
    for (int nt = 0; nt < 4; nt++) {
        int wrow = (t < 2) ? (4 * l + nt) : (nt * 16 + l);
        int key = ((wrow >> 2) & 7) << 3;
#pragma unroll
        for (int kk = 0; kk < 2; kk++)
            wf[nt][kk] = *(const s8v*)(sm + ((wrow * 64 + kk * 32 + qd * 8) ^ key));
    }

    const f4v fz = {0.f, 0.f, 0.f, 0.f};
    f4v acc[2][4];
#pragma unroll
    for (int mt = 0; mt < 2; mt++)
#pragma unroll
        for (int nt = 0; nt < 4; nt++) acc[mt][nt] = fz;

#pragma unroll
    for (int kk = 0; kk < 2; kk++)
#pragma unroll
        for (int nt = 0; nt < 4; nt++)
#pragma unroll
            for (int mt = 0; mt < 2; mt++)
                acc[mt][nt] = MFMA(a[mt][kk], wf[nt][kk], acc[mt][nt], 0, 0, 0);

    // fold softmax scale * log2(e) into Q so attention uses exp2 directly
    const float SC = 0.125f * 1.442695041f;

    if (t == 0) {
        float bbs[4];
#pragma unroll
        for (int nt = 0; nt < 4; nt++) bbs[nt] = bias[4 * l + nt];
#pragma unroll
        for (int mt = 0; mt < 2; mt++)
#pragma unroll
            for (int r = 0; r < 4; r++) {
                int s = s0 + mt * 16 + qd * 4 + r;
                s4v pk;
#pragma unroll
                for (int nt = 0; nt < 4; nt++)
                    pk[nt] = f2bf((acc[mt][nt][r] + bbs[nt]) * SC);
                *(s4v*)(qp + ((size_t)(b * 8 + h) * S_LEN + s) * 64 + 4 * l) = pk;
            }
        return;
    }

    __syncthreads();   // all wf reads done before sm is overwritten

    if (t == 1) {
        // ksm[s_local][e], stride 64, swizzle key (s_local>>2)&7
        float bbs[4];
#pragma unroll
        for (int nt = 0; nt < 4; nt++) bbs[nt] = bias[4 * l + nt];
#pragma unroll
        for (int mt = 0; mt < 2; mt++)
#pragma unroll
            for (int r = 0; r < 4; r++) {
                int sl = w * 32 + mt * 16 + qd * 4 + r;
                s4v pk;
#pragma unroll
                for (int nt = 0; nt < 4; nt++) pk[nt] = f2bf(acc[mt][nt][r] + bbs[nt]);
                int sidx = (sl * 64 + 4 * l) ^ (((sl >> 2) & 7) << 3);
                *(s4v*)(sm + sidx) = pk;
            }
    } else {
        // vsm[e][s_local], stride 128, swizzle key (e>>2)&7
#pragma unroll
        for (int nt = 0; nt < 4; nt++) {
            float bb = bias[nt * 16 + l];
            int e = nt * 16 + l;
            int key = ((e >> 2) & 7) << 3;
#pragma unroll
            for (int mt = 0; mt < 2; mt++) {
                s4v pk;
#pragma unroll
                for (int r = 0; r < 4; r++) pk[r] = f2bf(acc[mt][nt][r] + bb);
                int sidx = (e * 128 + w * 32 + mt * 16 + qd * 4) ^ key;
                *(s4v*)(sm + sidx) = pk;
            }
        }
    }
    __syncthreads();

    // ---- frag-order gather + coalesced stores (2 tiles x 8 chunks x 1KB) ----
    short* dst = (t == 1) ? kfrag : vfrag;
    const size_t obase0 = ((size_t)(b * 8 + h) * 32 + qt * 2) * 4096;
    const int f = threadIdx.x & 63, cp = threadIdx.x >> 6;
    const int fl = f & 15, fq = f >> 4;
#pragma unroll
    for (int tt = 0; tt < 2; tt++)
#pragma unroll
        for (int ci = 0; ci < 2; ci++) {
            int c = cp + ci * 4;
            int n2 = c >> 1, kk = c & 1;
            int sidx;
            if (t == 1) {
                int sl = tt * 64 + 4 * fl + n2;
                sidx = (sl * 64 + kk * 32 + fq * 8) ^ (((sl >> 2) & 7) << 3);
            } else {
                int e = 4 * fl + n2;
                sidx = (e * 128 + tt * 64 + kk * 32 + fq * 8) ^ (((e >> 2) & 7) << 3);
            }
            s8v x = *(const s8v*)(sm + sidx);
            *(s8v*)(dst + obase0 + tt * 4096 + c * 512 + f * 8) = x;
        }
}

// ---------------- flash attention v14: barrier-free, 8 independent wave-streams -------
// Ledger: attn moved only with stream count (v7) and barrier count (v12); byte
// volumes / balance / PV pipelining all neutral. Diagnosis: the K-staging barrier
// collapses the block's 4 waves into one lockstep stream -> only 2 independent
// streams/CU. Fix: drop LDS staging entirely; each wave reads K AND V fragments
// straight from L2 (frag layout = coalesced 1KB/instr) with a register double
// buffer prefetching tile kb+1 during tile kb (unroll-by-2, named reg sets).
// ZERO __syncthreads -> 8 fully independent wave-streams/CU. Extra K L2 traffic
// ~0.5GB stays under the 34.5 TB/s aggregate ceiling, XCD-affine via h=gid&7.
__global__ __launch_bounds__(256) void attn_kernel(
    const short* __restrict__ qp, const short* __restrict__ kfrag,
    const short* __restrict__ vfrag,
    const int* __restrict__ valid_lens, short* __restrict__ ctx)
{
    __shared__ alignas(16) short lP[4][32 * 72];  // per-wave P scratch, stride 72

    const int gid = blockIdx.x;
    const int h  = gid & 7;            // gid%8 -> XCD heuristic for K/V L2 locality
    int b        = (gid >> 3) & 3;
    const int qt = gid >> 5;           // 0..15, 128 rows per block
    b ^= 3 * ((gid >> 8) & 1);         // pair (b, b^3) batches on each CU: vlen balance
    const int w = threadIdx.x >> 6, lane = threadIdx.x & 63;
    const int l = lane & 15, qd = lane >> 4;
    const int vlen = valid_lens[b];
    const int ntiles = (vlen + 63) >> 6;   // skip fully-masked tiles: exp==0 exactly

    const int bh = b * 8 + h;
    const short* Qs = qp + (size_t)bh * S_LEN * 64;
    const short* Kf = kfrag + (size_t)bh * 32 * 4096 + lane * 8;
    const short* Vf = vfrag + (size_t)bh * 32 * 4096 + lane * 8;

    const int s0 = qt * 128 + w * 32;
    s8v qf[2][2];
#pragma unroll
    for (int mt = 0; mt < 2; mt++)
#pragma unroll
        for (int kk = 0; kk < 2; kk++)
            qf[mt][kk] = *(const s8v*)(Qs + (size_t)(s0 + mt * 16 + l) * 64 + kk * 32 + qd * 8);

    const f4v fz = {0.f, 0.f, 0.f, 0.f};
    f4v O[2][4];
    float lsum[2][4];
#pragma unroll
    for (int mt = 0; mt < 2; mt++)
#pragma unroll
        for (int r = 0; r < 4; r++) lsum[mt][r] = 0.f;
#pragma unroll
    for (int mt = 0; mt < 2; mt++)
#pragma unroll
        for (int ne = 0; ne < 4; ne++) O[mt][ne] = fz;

    short* lPw = lP[w];

    s8v kA[4][2], vA[4][2], kB[4][2], vB[4][2];   // register double buffer

    auto LOAD = [&](s8v (&kf)[4][2], s8v (&vf)[4][2], int kb) {
        const short* Kb = Kf + (size_t)kb * 4096;
        const short* Vb = Vf + (size_t)kb * 4096;
#pragma unroll
        for (int c = 0; c < 8; c++) {
            kf[c >> 1][c & 1] = *(const s8v*)(Kb + c * 512);
            vf[c >> 1][c & 1] = *(const s8v*)(Vb + c * 512);
        }
    };

    auto BODY = [&](const s8v (&kf)[4][2], const s8v (&vf)[4][2], int kb) {
        f4v sf[2][4];
#pragma unroll
        for (int mt = 0; mt < 2; mt++)
#pragma unroll
            for (int nt = 0; nt < 4; nt++) sf[mt][nt] = fz;
        __builtin_amdgcn_s_setprio(1);
#pragma unroll
        for (int nt = 0; nt < 4; nt++)
#pragma unroll
            for (int mt = 0; mt < 2; mt++) {
                sf[mt][nt] = MFMA(qf[mt][0], kf[nt][0], sf[mt][nt], 0, 0, 0);
                sf[mt][nt] = MFMA(qf[mt][1], kf[nt][1], sf[mt][nt], 0, 0, 0);
            }
        __builtin_amdgcn_s_setprio(0);

        // boundary-tile key mask (key at (nt,l) = kb*64 + 4*l + nt)
        if (kb == ntiles - 1 && (vlen & 63)) {
            int rem = vlen - kb * 64;
#pragma unroll
            for (int nt = 0; nt < 4; nt++)
                if (4 * l + nt >= rem) {
#pragma unroll
                    for (int mt = 0; mt < 2; mt++)
#pragma unroll
                        for (int r = 0; r < 4; r++) sf[mt][nt][r] = -1e30f;
                }
        }

        // softmax, no max subtraction; truncating bf16 pack; ds_write_b64/row-reg
#pragma unroll
        for (int mt = 0; mt < 2; mt++)
#pragma unroll
            for (int r = 0; r < 4; r++) {
                float p0 = __builtin_amdgcn_exp2f(sf[mt][0][r]);
                float p1 = __builtin_amdgcn_exp2f(sf[mt][1][r]);
                float p2 = __builtin_amdgcn_exp2f(sf[mt][2][r]);
                float p3 = __builtin_amdgcn_exp2f(sf[mt][3][r]);
                lsum[mt][r] += (p0 + p1) + (p2 + p3);
                i2v pk;
                pk[0] = (int)pack_bf2_trunc(p0, p1);
                pk[1] = (int)pack_bf2_trunc(p2, p3);
                *(i2v*)(lPw + (mt * 16 + qd * 4 + r) * 72 + 4 * l) = pk;
            }

        // O += P V  (A-frags from wave-private LDS; in-wave lgkm ordering only)
        s8v pa[2][2];
#pragma unroll
        for (int mt = 0; mt < 2; mt++)
#pragma unroll
            for (int kk = 0; kk < 2; kk++)
                pa[mt][kk] = *(const s8v*)(lPw + (mt * 16 + l) * 72 + kk * 32 + qd * 8);
        __builtin_amdgcn_s_setprio(1);
#pragma unroll
        for (int ne = 0; ne < 4; ne++)
#pragma unroll
            for (int mt = 0; mt < 2; mt++) {
                O[mt][ne] = MFMA(pa[mt][0], vf[ne][0], O[mt][ne], 0, 0, 0);
                O[mt][ne] = MFMA(pa[mt][1], vf[ne][1], O[mt][ne], 0, 0, 0);
            }
        __builtin_amdgcn_s_setprio(0);
    };

    LOAD(kA, vA, 0);
    for (int kb = 0; kb < ntiles; kb += 2) {
        if (kb + 1 < ntiles) LOAD(kB, vB, kb + 1);     // prefetch flies under BODY(A)
        BODY(kA, vA, kb);
        if (kb + 1 < ntiles) {
            if (kb + 2 < ntiles) LOAD(kA, vA, kb + 2); // prefetch flies under BODY(B)
            BODY(kB, vB, kb + 1);
        }
    }

    // normalize + write ctx[b][s][h*64 + e] (bf16), packed 8B stores (e = 4*l+ne)
#pragma unroll
    for (int mt = 0; mt < 2; mt++)
#pragma unroll
        for (int r = 0; r < 4; r++) {
            float inv = 1.0f / rowsum16(lsum[mt][r]);
            int s = s0 + mt * 16 + qd * 4 + r;
            s4v pk;
#pragma unroll
            for (int ne = 0; ne < 4; ne++) pk[ne] = f2bf(O[mt][ne][r] * inv);
            *(s4v*)(ctx + ((size_t)(b * S_LEN + s)) * 512 + h * 64 + 4 * l) = pk;
        }
}

// ---------------- output projection: [8192,512] = ctx @ Wo + bo ----------------
__global__ __launch_bounds__(256) void outproj_kernel(
    const short* __restrict__ ctx, const short* __restrict__ WoT,
    const float* __restrict__ bo, float* __restrict__ out)
{
    __shared__ short lB[64 * 520];   // Wo^T tile, padded stride (kills 1024B-stride alias)
    __shared__ short lA[128 * 40];   // A k-slab, padded stride 40 shorts (80B)

    const int rb = blockIdx.x * 128;
    const int nb = blockIdx.y * 64;
    const int w = threadIdx.x >> 6, lane = threadIdx.x & 63;
    const int l = lane & 15, qd = lane >> 4;

    {   // stage B tile once: 64 rows x 512
        int n = threadIdx.x >> 2, c0 = threadIdx.x & 3;
#pragma unroll
        for (int i = 0; i < 16; i++) {
            int g = i * 4 + c0;  // 64 granules of 8 shorts
            i4v x = *(const i4v*)(WoT + (size_t)(nb + n) * 512 + g * 8);
            *(i4v*)(lB + n * 520 + g * 8) = x;
        }
    }
    __syncthreads();

    const f4v fz = {0.f, 0.f, 0.f, 0.f};
    f4v acc[2][4];
#pragma unroll
    for (int mt = 0; mt < 2; mt++)
#pragma unroll
        for (int nt = 0; nt < 4; nt++) acc[mt][nt] = fz;

    for (int ko = 0; ko < 16; ko++) {
        {   // stage A slab 128x32
            int r = threadIdx.x >> 1, hp = threadIdx.x & 1;
            const short* src = ctx + (size_t)(rb + r) * 512 + ko * 32 + hp * 16;
            i4v x0 = *(const i4v*)src;
            i4v x1 = *(const i4v*)(src + 8);
            *(i4v*)(lA + r * 40 + hp * 16) = x0;
            *(i4v*)(lA + r * 40 + hp * 16 + 8) = x1;
        }
        __syncthreads();
        s8v af[2];
#pragma unroll
        for (int mt = 0; mt < 2; mt++)
            af[mt] = *(const s8v*)(lA + (w * 32 + mt * 16 + l) * 40 + qd * 8);
#pragma unroll
        for (int nt = 0; nt < 4; nt++) {
            s8v bfr = *(const s8v*)(lB + (nt * 16 + l) * 520 + ko * 32 + qd * 8);
#pragma unroll
            for (int mt = 0; mt < 2; mt++)
                acc[mt][nt] = MFMA(af[mt], bfr, acc[mt][nt], 0, 0, 0);
        }
        __syncthreads();
    }

#pragma unroll
    for (int nt = 0; nt < 4; nt++) {
        float bias = bo[nb + nt * 16 + l];
#pragma unroll
        for (int mt = 0; mt < 2; mt++)
#pragma unroll
            for (int r = 0; r < 4; r++) {
                int row = rb + w * 32 + mt * 16 + qd * 4 + r;
                out[(size_t)row * 512 + nb + nt * 16 + l] = acc[mt][nt][r] + bias;
            }
    }
}

extern "C" void kernel_launch(void* const* d_in, const int* in_sizes, int n_in,
                              void* d_out, int out_size, void* d_ws, size_t ws_size,
                              hipStream_t stream)
{
    const float* q  = (const float*)d_in[0];
    const float* k  = (const float*)d_in[1];
    const float* v  = (const float*)d_in[2];
    const float* Wq = (const float*)d_in[3];
    const float* bq = (const float*)d_in[4];
    const float* Wk = (const float*)d_in[5];
    const float* bk = (const float*)d_in[6];
    const float* Wv = (const float*)d_in[7];
    const float* bv = (const float*)d_in[8];
    const float* Wo = (const float*)d_in[9];
    const float* bo = (const float*)d_in[10];
    const int*   vl = (const int*)d_in[11];
    float* out = (float*)d_out;

    char* ws = (char*)d_ws;
    const size_t SL = (size_t)4 * 8 * S_LEN * 64 * sizeof(short);  // 8 MiB per tensor
    short* qp    = (short*)(ws);            // proj -> attn
    short* ctx   = (short*)(ws + SL);       // attn -> outproj
    short* kfrag = (short*)(ws + 2 * SL);   // proj -> attn
    short* vfrag = (short*)(ws + 3 * SL);   // proj -> attn
    short* WoT   = (short*)(ws + 4 * SL);   // proj(z=12) -> outproj

    proj_kernel<<<dim3(16, 8, 13), 256, 0, stream>>>(q, k, v, Wq, Wk, Wv,
                                                     bq, bk, bv, Wo, WoT,
                                                     qp, kfrag, vfrag);
    attn_kernel<<<512, 256, 0, stream>>>(qp, kfrag, vfrag, vl, ctx);
    outproj_kernel<<<dim3(64, 8), 256, 0, stream>>>(ctx, WoT, bo, out);
}

// Round 13
// 166.221 us; speedup vs baseline: 1.1147x; 1.1147x over previous
//
#include <hip/hip_runtime.h>

#define S_LEN 2048
#define D_MODEL 512

typedef __attribute__((ext_vector_type(8))) short s8v;   // 8 x bf16 (4 VGPRs) MFMA A/B frag
typedef __attribute__((ext_vector_type(4))) float f4v;   // MFMA C/D frag
typedef __attribute__((ext_vector_type(4))) short s4v;
typedef __attribute__((ext_vector_type(4))) int   i4v;
typedef __attribute__((ext_vector_type(2))) int   i2v;

#define MFMA __builtin_amdgcn_mfma_f32_16x16x32_bf16

__device__ inline short f2bf(float x) {            // fp32 -> bf16 RNE
    union { float f; unsigned u; } v; v.f = x;
    unsigned r = v.u + 0x7fffu + ((v.u >> 16) & 1u);
    return (short)(r >> 16);
}
__device__ inline unsigned pack_bf2_trunc(float a, float b) { // truncating pack: 3 inst
    unsigned ua = __builtin_bit_cast(unsigned, a);
    unsigned ub = __builtin_bit_cast(unsigned, b);
    return (ua >> 16) | (ub & 0xffff0000u);
}

template <int C>
__device__ inline float dppf(float x) {            // DPP permute within 16-lane row
    int i = __builtin_bit_cast(int, x);
    i = __builtin_amdgcn_update_dpp(0, i, C, 0xF, 0xF, true);
    return __builtin_bit_cast(float, i);
}
__device__ inline float rowsum16(float x) {
    x += dppf<0xB1>(x);
    x += dppf<0x4E>(x);
    x += dppf<0x141>(x);
    x += dppf<0x140>(x);
    return x;
}

// async global->LDS, 16B per lane. LDS dest is wave-uniform base + lane*16
// (per-lane pointers computed as base + tid*16 satisfy this layout).
typedef const __attribute__((address_space(1))) void* gptr_t;
typedef __attribute__((address_space(3))) void* sptr_t;
__device__ inline void gload16(const void* g, void* s) {
    __builtin_amdgcn_global_load_lds((gptr_t)g, (sptr_t)s, 16, 0, 0);
}

// ---------------- prep: Wo transpose to bf16 (LDS-tiled, coalesced) ----------------
__global__ __launch_bounds__(256) void prep_kernel(
    const float* __restrict__ Wo, short* __restrict__ WoT)
{
    __shared__ short t[64 * 65];
    const int bi = (blockIdx.x >> 3) * 64;   // input-dim base (i)
    const int bj = (blockIdx.x & 7) * 64;    // output-dim base (o)
    const int c = threadIdx.x & 63, rr = threadIdx.x >> 6;
#pragma unroll
    for (int r = 0; r < 16; r++) {
        int i = r * 4 + rr;
        t[c * 65 + i] = f2bf(Wo[(size_t)(bi + i) * 512 + bj + c]);  // coalesced read
    }
    __syncthreads();
#pragma unroll
    for (int r = 0; r < 16; r++) {
        int o = r * 4 + rr;
        WoT[(size_t)(bj + o) * 512 + bi + c] = t[o * 65 + c];       // coalesced write
    }
}

// ---------------- fused projections+repack: qp [b][h][s][64], kfrag/vfrag tiles -------
// Each block covers 128 rows = exactly two 64-key frag tiles, so K/V frag
// reordering happens in-block: acc -> LDS (s,e) tile -> frag-order gather ->
// coalesced 1KB stores. LDS XOR swizzle keyed on ((row>>2)&7), write AND read.
__global__ __launch_bounds__(256) void proj_kernel(
    const float* __restrict__ q, const float* __restrict__ k, const float* __restrict__ v,
    const float* __restrict__ Wq, const float* __restrict__ Wk, const float* __restrict__ Wv,
    const float* __restrict__ bq, const float* __restrict__ bk, const float* __restrict__ bv,
    short* __restrict__ qp, short* __restrict__ kfrag, short* __restrict__ vfrag)
{
    __shared__ short sm[128 * 64];     // 16 KB union: wsm[64][64] -> ksm[128][64]/vsm[64][128]

    const int t = blockIdx.z >> 2;     // 0:q 1:k 2:v
    const int b = blockIdx.z & 3;
    const int h = blockIdx.y;
    const int qt = blockIdx.x;         // 16 row-tiles of 128
    const int w = threadIdx.x >> 6, lane = threadIdx.x & 63;
    const int l = lane & 15, qd = lane >> 4;

    const float* X    = (t == 0) ? q  : (t == 1) ? k  : v;
    const float* Wp   = (t == 0) ? Wq : (t == 1) ? Wk : Wv;
    const float* bias = (t == 0) ? bq : (t == 1) ? bk : bv;

    // ---- stage wsm[e][d] = W[d][e] (bf16, row-swizzled) ----
    {
        const int d = threadIdx.x >> 2, c4 = threadIdx.x & 3;   // 16 cols per thread
        const float* src = Wp + d * 64 + c4 * 16;
        f4v x0 = *(const f4v*)(src);
        f4v x1 = *(const f4v*)(src + 4);
        f4v x2 = *(const f4v*)(src + 8);
        f4v x3 = *(const f4v*)(src + 12);
        float xs[16] = {x0[0],x0[1],x0[2],x0[3], x1[0],x1[1],x1[2],x1[3],
                        x2[0],x2[1],x2[2],x2[3], x3[0],x3[1],x3[2],x3[3]};
#pragma unroll
        for (int j = 0; j < 16; j++) {
            int e = c4 * 16 + j;
            int sidx = (e * 64 + d) ^ (((e >> 2) & 7) << 3);
            sm[sidx] = f2bf(xs[j]);
        }
    }
    __syncthreads();

    const int s0 = qt * 128 + w * 32;

    // A frags direct from global fp32, converted
    s8v a[2][2];
#pragma unroll
    for (int mt = 0; mt < 2; mt++)
#pragma unroll
        for (int kk = 0; kk < 2; kk++) {
            const float* p = X + (size_t)(b * S_LEN + s0 + mt * 16 + l) * 512 + h * 64 + kk * 32 + qd * 8;
            f4v x0 = *(const f4v*)p;
            f4v x1 = *(const f4v*)(p + 4);
            s8v fr;
            fr[0] = f2bf(x0[0]); fr[1] = f2bf(x0[1]); fr[2] = f2bf(x0[2]); fr[3] = f2bf(x0[3]);
            fr[4] = f2bf(x1[0]); fr[5] = f2bf(x1[1]); fr[6] = f2bf(x1[2]); fr[7] = f2bf(x1[3]);
            a[mt][kk] = fr;
        }
    // B frags from wsm: q/k use e = 4*l + nt, v uses e = nt*16 + l
    s8v wf[4][2];
#pragma unroll
    for (int nt = 0; nt < 4; nt++) {
        int wrow = (t < 2) ? (4 * l + nt) : (nt * 16 + l);
        int key = ((wrow >> 2) & 7) << 3;
#pragma unroll
        for (int kk = 0; kk < 2; kk++)
            wf[nt][kk] = *(const s8v*)(sm + ((wrow * 64 + kk * 32 + qd * 8) ^ key));
    }

    const f4v fz = {0.f, 0.f, 0.f, 0.f};
    f4v acc[2][4];
#pragma unroll
    for (int mt = 0; mt < 2; mt++)
#pragma unroll
        for (int nt = 0; nt < 4; nt++) acc[mt][nt] = fz;

#pragma unroll
    for (int kk = 0; kk < 2; kk++)
#pragma unroll
        for (int nt = 0; nt < 4; nt++)
#pragma unroll
            for (int mt = 0; mt < 2; mt++)
                acc[mt][nt] = MFMA(a[mt][kk], wf[nt][kk], acc[mt][nt], 0, 0, 0);

    // fold softmax scale * log2(e) into Q so attention uses exp2 directly
    const float SC = 0.125f * 1.442695041f;

    if (t == 0) {
        float bbs[4];
#pragma unroll
        for (int nt = 0; nt < 4; nt++) bbs[nt] = bias[4 * l + nt];
#pragma unroll
        for (int mt = 0; mt < 2; mt++)
#pragma unroll
            for (int r = 0; r < 4; r++) {
                int s = s0 + mt * 16 + qd * 4 + r;
                s4v pk;
#pragma unroll
                for (int nt = 0; nt < 4; nt++)
                    pk[nt] = f2bf((acc[mt][nt][r] + bbs[nt]) * SC);
                *(s4v*)(qp + ((size_t)(b * 8 + h) * S_LEN + s) * 64 + 4 * l) = pk;
            }
        return;
    }

    __syncthreads();   // all wf reads done before sm is overwritten

    if (t == 1) {
        // ksm[s_local][e], stride 64, swizzle key (s_local>>2)&7
        float bbs[4];
#pragma unroll
        for (int nt = 0; nt < 4; nt++) bbs[nt] = bias[4 * l + nt];
#pragma unroll
        for (int mt = 0; mt < 2; mt++)
#pragma unroll
            for (int r = 0; r < 4; r++) {
                int sl = w * 32 + mt * 16 + qd * 4 + r;
                s4v pk;
#pragma unroll
                for (int nt = 0; nt < 4; nt++) pk[nt] = f2bf(acc[mt][nt][r] + bbs[nt]);
                int sidx = (sl * 64 + 4 * l) ^ (((sl >> 2) & 7) << 3);
                *(s4v*)(sm + sidx) = pk;
            }
    } else {
        // vsm[e][s_local], stride 128, swizzle key (e>>2)&7
#pragma unroll
        for (int nt = 0; nt < 4; nt++) {
            float bb = bias[nt * 16 + l];
            int e = nt * 16 + l;
            int key = ((e >> 2) & 7) << 3;
#pragma unroll
            for (int mt = 0; mt < 2; mt++) {
                s4v pk;
#pragma unroll
                for (int r = 0; r < 4; r++) pk[r] = f2bf(acc[mt][nt][r] + bb);
                int sidx = (e * 128 + w * 32 + mt * 16 + qd * 4) ^ key;
                *(s4v*)(sm + sidx) = pk;
            }
        }
    }
    __syncthreads();

    // ---- frag-order gather + coalesced stores (2 tiles x 8 chunks x 1KB) ----
    short* dst = (t == 1) ? kfrag : vfrag;
    const size_t obase0 = ((size_t)(b * 8 + h) * 32 + qt * 2) * 4096;
    const int f = threadIdx.x & 63, cp = threadIdx.x >> 6;
    const int fl = f & 15, fq = f >> 4;
#pragma unroll
    for (int tt = 0; tt < 2; tt++)
#pragma unroll
        for (int ci = 0; ci < 2; ci++) {
            int c = cp + ci * 4;
            int n2 = c >> 1, kk = c & 1;
            int sidx;
            if (t == 1) {
                int sl = tt * 64 + 4 * fl + n2;
                sidx = (sl * 64 + kk * 32 + fq * 8) ^ (((sl >> 2) & 7) << 3);
            } else {
                int e = 4 * fl + n2;
                sidx = (e * 128 + tt * 64 + kk * 32 + fq * 8) ^ (((e >> 2) & 7) << 3);
            }
            s8v x = *(const s8v*)(sm + sidx);
            *(s8v*)(dst + obase0 + tt * 4096 + c * 512 + f * 8) = x;
        }
}

// ---------------- flash attention v12: KVBLK=128, one barrier per 128 keys ------------
// v6-v11: attn pinned at 40-42us across LDS/L2/balance/pipeline variants -> the
// floor is fixed per-iteration overhead (barrier + vmcnt/lgkm drain + refill).
// v12: 128 keys per iteration (two sequential 64-key halves, V-issue-early in
// each) sharing ONE barrier -> best measured attn (<40.8us). v14 (barrier-free,
// per-wave K from L2, reg dbuf) regressed to 60us: K-sharing via LDS is worth
// more than stream independence. K staged 16KB/iter dbuf (LDS 50KB); V direct
// from L2; b^3 pairing; setprio. Grid 512x256.
__global__ __launch_bounds__(256, 2) void attn_kernel(
    const short* __restrict__ qp, const short* __restrict__ kfrag,
    const short* __restrict__ vfrag,
    const int* __restrict__ valid_lens, short* __restrict__ ctx)
{
    __shared__ alignas(16) short kbuf[2][8192];   // 16 KB K tile (128 keys), dbuf
    __shared__ alignas(16) short lP[4][32 * 72];  // per-wave P scratch, stride 72

    const int gid = blockIdx.x;
    const int h  = gid & 7;            // gid%8 -> XCD heuristic for K/V L2 locality
    int b        = (gid >> 3) & 3;
    const int qt = gid >> 5;           // 0..15, 128 rows per block
    b ^= 3 * ((gid >> 8) & 1);         // pair (b, b^3) batches on each CU: vlen balance
    const int w = threadIdx.x >> 6, lane = threadIdx.x & 63;
    const int l = lane & 15, qd = lane >> 4;
    const int vlen = valid_lens[b];
    const int nt2 = (vlen + 127) >> 7; // 128-key iterations; masked tail exact (exp2->0)

    const int bh = b * 8 + h;
    const short* Qs = qp + (size_t)bh * S_LEN * 64;
    const short* Kf = kfrag + (size_t)bh * 32 * 4096;
    const short* Vf = vfrag + (size_t)bh * 32 * 4096;

    const int s0 = qt * 128 + w * 32;
    s8v qf[2][2];
#pragma unroll
    for (int mt = 0; mt < 2; mt++)
#pragma unroll
        for (int kk = 0; kk < 2; kk++)
            qf[mt][kk] = *(const s8v*)(Qs + (size_t)(s0 + mt * 16 + l) * 64 + kk * 32 + qd * 8);

    const f4v fz = {0.f, 0.f, 0.f, 0.f};
    f4v O[2][4];
    float lsum[2][4];
#pragma unroll
    for (int mt = 0; mt < 2; mt++)
#pragma unroll
        for (int r = 0; r < 4; r++) lsum[mt][r] = 0.f;
#pragma unroll
    for (int mt = 0; mt < 2; mt++)
#pragma unroll
        for (int ne = 0; ne < 4; ne++) O[mt][ne] = fz;

    short* lPw = lP[w];
    const int toff = threadIdx.x * 8;  // 16B per thread; 4KB per gload round

    // prologue: stage K tiles 0,1 (16KB) into buffer 0
#pragma unroll
    for (int r = 0; r < 4; r++)
        gload16(Kf + r * 2048 + toff, &kbuf[0][r * 2048 + toff]);
    __syncthreads();   // compiler emits vmcnt(0) drain before s_barrier

    for (int j = 0; j < nt2; j++) {
        const int cur = j & 1;
        // issue next-128-key K prefetch FIRST so it flies under this iter's compute
        if (j + 1 < nt2) {
            const short* Ks = Kf + (size_t)(j + 1) * 8192;
#pragma unroll
            for (int r = 0; r < 4; r++)
                gload16(Ks + r * 2048 + toff, &kbuf[cur ^ 1][r * 2048 + toff]);
        }

        // two sequential 64-key halves, one barrier for both
#pragma unroll
        for (int st = 0; st < 2; st++) {
            const int kb = 2 * j + st;

            // V fragments straight from global (L2-resident, coalesced 1KB/instr);
            // issued first, consumed after softmax -> QK+softmax covers L2 latency.
            const short* Vb = Vf + (size_t)kb * 4096 + lane * 8;
            s8v vf[4][2];
#pragma unroll
            for (int ne = 0; ne < 4; ne++)
#pragma unroll
                for (int kk = 0; kk < 2; kk++)
                    vf[ne][kk] = *(const s8v*)(Vb + (ne * 2 + kk) * 512);

            // K fragments from LDS: contiguous 1KB per chunk, conflict-free
            const short* Kb = &kbuf[cur][st * 4096 + lane * 8];
            s8v kf[4][2];
#pragma unroll
            for (int nt = 0; nt < 4; nt++)
#pragma unroll
                for (int kk = 0; kk < 2; kk++)
                    kf[nt][kk] = *(const s8v*)(Kb + (nt * 2 + kk) * 512);

            f4v sf[2][4];
#pragma unroll
            for (int mt = 0; mt < 2; mt++)
#pragma unroll
                for (int nt = 0; nt < 4; nt++) sf[mt][nt] = fz;
            __builtin_amdgcn_s_setprio(1);
#pragma unroll
            for (int nt = 0; nt < 4; nt++)
#pragma unroll
                for (int mt = 0; mt < 2; mt++) {
                    sf[mt][nt] = MFMA(qf[mt][0], kf[nt][0], sf[mt][nt], 0, 0, 0);
                    sf[mt][nt] = MFMA(qf[mt][1], kf[nt][1], sf[mt][nt], 0, 0, 0);
                }
            __builtin_amdgcn_s_setprio(0);

            // boundary mask (key at (nt,l) = kb*64 + 4*l + nt); rem<=0 -> all masked
            if (j == nt2 - 1) {
                int rem = vlen - kb * 64;
                if (rem < 64) {
#pragma unroll
                    for (int nt = 0; nt < 4; nt++)
                        if (4 * l + nt >= rem) {
#pragma unroll
                            for (int mt = 0; mt < 2; mt++)
#pragma unroll
                                for (int r = 0; r < 4; r++) sf[mt][nt][r] = -1e30f;
                        }
                }
            }

            // softmax, no max subtraction; truncating bf16 pack; ds_write_b64/row-reg
#pragma unroll
            for (int mt = 0; mt < 2; mt++)
#pragma unroll
                for (int r = 0; r < 4; r++) {
                    float p0 = __builtin_amdgcn_exp2f(sf[mt][0][r]);
                    float p1 = __builtin_amdgcn_exp2f(sf[mt][1][r]);
                    float p2 = __builtin_amdgcn_exp2f(sf[mt][2][r]);
                    float p3 = __builtin_amdgcn_exp2f(sf[mt][3][r]);
                    lsum[mt][r] += (p0 + p1) + (p2 + p3);
                    i2v pk;
                    pk[0] = (int)pack_bf2_trunc(p0, p1);
                    pk[1] = (int)pack_bf2_trunc(p2, p3);
                    *(i2v*)(lPw + (mt * 16 + qd * 4 + r) * 72 + 4 * l) = pk;
                }

            // O += P V  (A-frags from wave-private LDS; in-wave lgkm ordering)
            s8v pa[2][2];
#pragma unroll
            for (int mt = 0; mt < 2; mt++)
#pragma unroll
                for (int kk = 0; kk < 2; kk++)
                    pa[mt][kk] = *(const s8v*)(lPw + (mt * 16 + l) * 72 + kk * 32 + qd * 8);
            __builtin_amdgcn_s_setprio(1);
#pragma unroll
            for (int ne = 0; ne < 4; ne++)
#pragma unroll
                for (int mt = 0; mt < 2; mt++) {
                    O[mt][ne] = MFMA(pa[mt][0], vf[ne][0], O[mt][ne], 0, 0, 0);
                    O[mt][ne] = MFMA(pa[mt][1], vf[ne][1], O[mt][ne], 0, 0, 0);
                }
            __builtin_amdgcn_s_setprio(0);
        }

        // all waves done reading kbuf[cur]; K prefetch into kbuf[cur^1] drained here
        __syncthreads();
    }

    // normalize + write ctx[b][s][h*64 + e] (bf16), packed 8B stores (e = 4*l+ne)
#pragma unroll
    for (int mt = 0; mt < 2; mt++)
#pragma unroll
        for (int r = 0; r < 4; r++) {
            float inv = 1.0f / rowsum16(lsum[mt][r]);
            int s = s0 + mt * 16 + qd * 4 + r;
            s4v pk;
#pragma unroll
            for (int ne = 0; ne < 4; ne++) pk[ne] = f2bf(O[mt][ne][r] * inv);
            *(s4v*)(ctx + ((size_t)(b * S_LEN + s)) * 512 + h * 64 + 4 * l) = pk;
        }
}

// ---------------- output projection v2: barrier-free K-loop, A direct from L2 ---------
// [8192,512] = ctx @ Wo + bo. The old loop staged a 128x32 A-slab in LDS with 2
// barriers per ko (32 barriers/block) -- the same barrier tax v12 exposed in
// attn. ctx is L2-hot (8MB), so A frags are read DIRECTLY from global (16B/lane
// gather, unroll-by-2 register prefetch); only the Wo^T tile stays in LDS
// (staged once, one barrier total). Waves run barrier-free through the K loop.
__global__ __launch_bounds__(256) void outproj_kernel(
    const short* __restrict__ ctx, const short* __restrict__ WoT,
    const float* __restrict__ bo, float* __restrict__ out)
{
    __shared__ short lB[64 * 520];   // Wo^T tile, padded stride (kills 1024B-stride alias)

    const int rb = blockIdx.x * 128;
    const int nb = blockIdx.y * 64;
    const int w = threadIdx.x >> 6, lane = threadIdx.x & 63;
    const int l = lane & 15, qd = lane >> 4;

    {   // stage B tile once: 64 rows x 512
        int n = threadIdx.x >> 2, c0 = threadIdx.x & 3;
#pragma unroll
        for (int i = 0; i < 16; i++) {
            int g = i * 4 + c0;  // 64 granules of 8 shorts
            i4v x = *(const i4v*)(WoT + (size_t)(nb + n) * 512 + g * 8);
            *(i4v*)(lB + n * 520 + g * 8) = x;
        }
    }
    __syncthreads();   // the only barrier in this kernel

    const f4v fz = {0.f, 0.f, 0.f, 0.f};
    f4v acc[2][4];
#pragma unroll
    for (int mt = 0; mt < 2; mt++)
#pragma unroll
        for (int nt = 0; nt < 4; nt++) acc[mt][nt] = fz;

    // per-lane A base: row = rb + w*32 + mt*16 + l, col = ko*32 + qd*8
    const short* actx0 = ctx + (size_t)(rb + w * 32 + l) * 512 + qd * 8;
    const short* actx1 = actx0 + (size_t)16 * 512;

    s8v afA[2], afB[2];
    afA[0] = *(const s8v*)(actx0);
    afA[1] = *(const s8v*)(actx1);

#pragma unroll
    for (int ko = 0; ko < 16; ko += 2) {
        // prefetch ko+1 while computing ko
        afB[0] = *(const s8v*)(actx0 + (ko + 1) * 32);
        afB[1] = *(const s8v*)(actx1 + (ko + 1) * 32);
#pragma unroll
        for (int nt = 0; nt < 4; nt++) {
            s8v bfr = *(const s8v*)(lB + (nt * 16 + l) * 520 + ko * 32 + qd * 8);
#pragma unroll
            for (int mt = 0; mt < 2; mt++)
                acc[mt][nt] = MFMA(afA[mt], bfr, acc[mt][nt], 0, 0, 0);
        }
        if (ko + 2 < 16) {   // prefetch ko+2 while computing ko+1
            afA[0] = *(const s8v*)(actx0 + (ko + 2) * 32);
            afA[1] = *(const s8v*)(actx1 + (ko + 2) * 32);
        }
#pragma unroll
        for (int nt = 0; nt < 4; nt++) {
            s8v bfr = *(const s8v*)(lB + (nt * 16 + l) * 520 + (ko + 1) * 32 + qd * 8);
#pragma unroll
            for (int mt = 0; mt < 2; mt++)
                acc[mt][nt] = MFMA(afB[mt], bfr, acc[mt][nt], 0, 0, 0);
        }
    }

#pragma unroll
    for (int nt = 0; nt < 4; nt++) {
        float bias = bo[nb + nt * 16 + l];
#pragma unroll
        for (int mt = 0; mt < 2; mt++)
#pragma unroll
            for (int r = 0; r < 4; r++) {
                int row = rb + w * 32 + mt * 16 + qd * 4 + r;
                out[(size_t)row * 512 + nb + nt * 16 + l] = acc[mt][nt][r] + bias;
            }
    }
}

extern "C" void kernel_launch(void* const* d_in, const int* in_sizes, int n_in,
                              void* d_out, int out_size, void* d_ws, size_t ws_size,
                              hipStream_t stream)
{
    const float* q  = (const float*)d_in[0];
    const float* k  = (const float*)d_in[1];
    const float* v  = (const float*)d_in[2];
    const float* Wq = (const float*)d_in[3];
    const float* bq = (const float*)d_in[4];
    const float* Wk = (const float*)d_in[5];
    const float* bk = (const float*)d_in[6];
    const float* Wv = (const float*)d_in[7];
    const float* bv = (const float*)d_in[8];
    const float* Wo = (const float*)d_in[9];
    const float* bo = (const float*)d_in[10];
    const int*   vl = (const int*)d_in[11];
    float* out = (float*)d_out;

    char* ws = (char*)d_ws;
    const size_t SL = (size_t)4 * 8 * S_LEN * 64 * sizeof(short);  // 8 MiB per tensor
    short* qp    = (short*)(ws);            // proj -> attn
    short* ctx   = (short*)(ws + SL);       // attn -> outproj
    short* kfrag = (short*)(ws + 2 * SL);   // proj -> attn
    short* vfrag = (short*)(ws + 3 * SL);   // proj -> attn
    short* WoT   = (short*)(ws + 4 * SL);   // prep -> outproj

    prep_kernel<<<64, 256, 0, stream>>>(Wo, WoT);
    proj_kernel<<<dim3(16, 8, 12), 256, 0, stream>>>(q, k, v, Wq, Wk, Wv,
                                                     bq, bk, bv, qp, kfrag, vfrag);
    attn_kernel<<<512, 256, 0, stream>>>(qp, kfrag, vfrag, vl, ctx);
    outproj_kernel<<<dim3(64, 8), 256, 0, stream>>>(ctx, WoT, bo, out);
}

// Round 14
// 166.050 us; speedup vs baseline: 1.1159x; 1.0010x over previous
//
#include <hip/hip_runtime.h>

#define S_LEN 2048
#define D_MODEL 512

typedef __attribute__((ext_vector_type(8))) short s8v;   // 8 x bf16 (4 VGPRs) MFMA A/B frag
typedef __attribute__((ext_vector_type(4))) float f4v;   // MFMA C/D frag
typedef __attribute__((ext_vector_type(4))) short s4v;
typedef __attribute__((ext_vector_type(4))) int   i4v;
typedef __attribute__((ext_vector_type(2))) int   i2v;

#define MFMA __builtin_amdgcn_mfma_f32_16x16x32_bf16

__device__ inline short f2bf(float x) {            // fp32 -> bf16 RNE
    union { float f; unsigned u; } v; v.f = x;
    unsigned r = v.u + 0x7fffu + ((v.u >> 16) & 1u);
    return (short)(r >> 16);
}
__device__ inline unsigned pack_bf2_trunc(float a, float b) { // truncating pack: 3 inst
    unsigned ua = __builtin_bit_cast(unsigned, a);
    unsigned ub = __builtin_bit_cast(unsigned, b);
    return (ua >> 16) | (ub & 0xffff0000u);
}

template <int C>
__device__ inline float dppf(float x) {            // DPP permute within 16-lane row
    int i = __builtin_bit_cast(int, x);
    i = __builtin_amdgcn_update_dpp(0, i, C, 0xF, 0xF, true);
    return __builtin_bit_cast(float, i);
}
__device__ inline float rowsum16(float x) {
    x += dppf<0xB1>(x);
    x += dppf<0x4E>(x);
    x += dppf<0x141>(x);
    x += dppf<0x140>(x);
    return x;
}

// async global->LDS, 16B per lane. LDS dest is wave-uniform base + lane*16
// (per-lane pointers computed as base + tid*16 satisfy this layout).
typedef const __attribute__((address_space(1))) void* gptr_t;
typedef __attribute__((address_space(3))) void* sptr_t;
__device__ inline void gload16(const void* g, void* s) {
    __builtin_amdgcn_global_load_lds((gptr_t)g, (sptr_t)s, 16, 0, 0);
}

// ---------------- prep: Wo transpose to bf16 (LDS-tiled, coalesced) ----------------
__global__ __launch_bounds__(256) void prep_kernel(
    const float* __restrict__ Wo, short* __restrict__ WoT)
{
    __shared__ short t[64 * 65];
    const int bi = (blockIdx.x >> 3) * 64;   // input-dim base (i)
    const int bj = (blockIdx.x & 7) * 64;    // output-dim base (o)
    const int c = threadIdx.x & 63, rr = threadIdx.x >> 6;
#pragma unroll
    for (int r = 0; r < 16; r++) {
        int i = r * 4 + rr;
        t[c * 65 + i] = f2bf(Wo[(size_t)(bi + i) * 512 + bj + c]);  // coalesced read
    }
    __syncthreads();
#pragma unroll
    for (int r = 0; r < 16; r++) {
        int o = r * 4 + rr;
        WoT[(size_t)(bj + o) * 512 + bi + c] = t[o * 65 + c];       // coalesced write
    }
}

// ---------------- fused K/V projections+repack: kfrag/vfrag tiles ---------------------
// Q-projection moved into attn (each attn block projects its own 128 q-rows),
// so this pass is K/V only: 8 z-slices (t2 0:k 1:v, b=z&3). Each block covers
// 128 rows = two 64-key frag tiles; reorder in-block via swizzled LDS.
__global__ __launch_bounds__(256) void proj_kernel(
    const float* __restrict__ k, const float* __restrict__ v,
    const float* __restrict__ Wk, const float* __restrict__ Wv,
    const float* __restrict__ bk, const float* __restrict__ bv,
    short* __restrict__ kfrag, short* __restrict__ vfrag)
{
    __shared__ short sm[128 * 64];     // 16 KB union: wsm[64][64] -> ksm[128][64]/vsm[64][128]

    const int t2 = blockIdx.z >> 2;    // 0:k 1:v
    const int b = blockIdx.z & 3;
    const int h = blockIdx.y;
    const int qt = blockIdx.x;         // 16 row-tiles of 128
    const int w = threadIdx.x >> 6, lane = threadIdx.x & 63;
    const int l = lane & 15, qd = lane >> 4;

    const float* X    = (t2 == 0) ? k  : v;
    const float* Wp   = (t2 == 0) ? Wk : Wv;
    const float* bias = (t2 == 0) ? bk : bv;

    // ---- stage wsm[e][d] = W[d][e] (bf16, row-swizzled) ----
    {
        const int d = threadIdx.x >> 2, c4 = threadIdx.x & 3;   // 16 cols per thread
        const float* src = Wp + d * 64 + c4 * 16;
        f4v x0 = *(const f4v*)(src);
        f4v x1 = *(const f4v*)(src + 4);
        f4v x2 = *(const f4v*)(src + 8);
        f4v x3 = *(const f4v*)(src + 12);
        float xs[16] = {x0[0],x0[1],x0[2],x0[3], x1[0],x1[1],x1[2],x1[3],
                        x2[0],x2[1],x2[2],x2[3], x3[0],x3[1],x3[2],x3[3]};
#pragma unroll
        for (int j = 0; j < 16; j++) {
            int e = c4 * 16 + j;
            int sidx = (e * 64 + d) ^ (((e >> 2) & 7) << 3);
            sm[sidx] = f2bf(xs[j]);
        }
    }
    __syncthreads();

    const int s0 = qt * 128 + w * 32;

    // A frags direct from global fp32, converted
    s8v a[2][2];
#pragma unroll
    for (int mt = 0; mt < 2; mt++)
#pragma unroll
        for (int kk = 0; kk < 2; kk++) {
            const float* p = X + (size_t)(b * S_LEN + s0 + mt * 16 + l) * 512 + h * 64 + kk * 32 + qd * 8;
            f4v x0 = *(const f4v*)p;
            f4v x1 = *(const f4v*)(p + 4);
            s8v fr;
            fr[0] = f2bf(x0[0]); fr[1] = f2bf(x0[1]); fr[2] = f2bf(x0[2]); fr[3] = f2bf(x0[3]);
            fr[4] = f2bf(x1[0]); fr[5] = f2bf(x1[1]); fr[6] = f2bf(x1[2]); fr[7] = f2bf(x1[3]);
            a[mt][kk] = fr;
        }
    // B frags: k uses e = 4*l + nt, v uses e = nt*16 + l
    s8v wf[4][2];
#pragma unroll
    for (int nt = 0; nt < 4; nt++) {
        int wrow = (t2 == 0) ? (4 * l + nt) : (nt * 16 + l);
        int key = ((wrow >> 2) & 7) << 3;
#pragma unroll
        for (int kk = 0; kk < 2; kk++)
            wf[nt][kk] = *(const s8v*)(sm + ((wrow * 64 + kk * 32 + qd * 8) ^ key));
    }

    const f4v fz = {0.f, 0.f, 0.f, 0.f};
    f4v acc[2][4];
#pragma unroll
    for (int mt = 0; mt < 2; mt++)
#pragma unroll
        for (int nt = 0; nt < 4; nt++) acc[mt][nt] = fz;

#pragma unroll
    for (int kk = 0; kk < 2; kk++)
#pragma unroll
        for (int nt = 0; nt < 4; nt++)
#pragma unroll
            for (int mt = 0; mt < 2; mt++)
                acc[mt][nt] = MFMA(a[mt][kk], wf[nt][kk], acc[mt][nt], 0, 0, 0);

    __syncthreads();   // all wf reads done before sm is overwritten

    if (t2 == 0) {
        // ksm[s_local][e], stride 64, swizzle key (s_local>>2)&7
        float bbs[4];
#pragma unroll
        for (int nt = 0; nt < 4; nt++) bbs[nt] = bias[4 * l + nt];
#pragma unroll
        for (int mt = 0; mt < 2; mt++)
#pragma unroll
            for (int r = 0; r < 4; r++) {
                int sl = w * 32 + mt * 16 + qd * 4 + r;
                s4v pk;
#pragma unroll
                for (int nt = 0; nt < 4; nt++) pk[nt] = f2bf(acc[mt][nt][r] + bbs[nt]);
                int sidx = (sl * 64 + 4 * l) ^ (((sl >> 2) & 7) << 3);
                *(s4v*)(sm + sidx) = pk;
            }
    } else {
        // vsm[e][s_local], stride 128, swizzle key (e>>2)&7
#pragma unroll
        for (int nt = 0; nt < 4; nt++) {
            float bb = bias[nt * 16 + l];
            int e = nt * 16 + l;
            int key = ((e >> 2) & 7) << 3;
#pragma unroll
            for (int mt = 0; mt < 2; mt++) {
                s4v pk;
#pragma unroll
                for (int r = 0; r < 4; r++) pk[r] = f2bf(acc[mt][nt][r] + bb);
                int sidx = (e * 128 + w * 32 + mt * 16 + qd * 4) ^ key;
                *(s4v*)(sm + sidx) = pk;
            }
        }
    }
    __syncthreads();

    // ---- frag-order gather + coalesced stores (2 tiles x 8 chunks x 1KB) ----
    short* dst = (t2 == 0) ? kfrag : vfrag;
    const size_t obase0 = ((size_t)(b * 8 + h) * 32 + qt * 2) * 4096;
    const int f = threadIdx.x & 63, cp = threadIdx.x >> 6;
    const int fl = f & 15, fq = f >> 4;
#pragma unroll
    for (int tt = 0; tt < 2; tt++)
#pragma unroll
        for (int ci = 0; ci < 2; ci++) {
            int c = cp + ci * 4;
            int n2 = c >> 1, kk = c & 1;
            int sidx;
            if (t2 == 0) {
                int sl = tt * 64 + 4 * fl + n2;
                sidx = (sl * 64 + kk * 32 + fq * 8) ^ (((sl >> 2) & 7) << 3);
            } else {
                int e = 4 * fl + n2;
                sidx = (e * 128 + tt * 64 + kk * 32 + fq * 8) ^ (((e >> 2) & 7) << 3);
            }
            s8v x = *(const s8v*)(sm + sidx);
            *(s8v*)(dst + obase0 + tt * 4096 + c * 512 + f * 8) = x;
        }
}

// ---------------- flash attention v15: fused Q-projection + v12 loop ------------------
// Each block projects its own 128 q-rows in the prologue (the q-third of the old
// proj pass): wsm staged into kbuf[1] (free until j=0 prefetch), Q-tile transposed
// through an lP alias (free until first softmax), overlapped with the async K
// tile-0 staging. Removes 4 of 12 proj z-slices and the 16MB qp round-trip.
// Loop = v12: KVBLK=128, one barrier per 128 keys, K LDS dbuf, V direct from L2,
// b^3 pairing, setprio. Grid 512x256.
__global__ __launch_bounds__(256, 2) void attn_kernel(
    const float* __restrict__ q, const float* __restrict__ Wq, const float* __restrict__ bq,
    const short* __restrict__ kfrag, const short* __restrict__ vfrag,
    const int* __restrict__ valid_lens, short* __restrict__ ctx)
{
    __shared__ alignas(16) short kbuf[2][8192];   // 16 KB K tile (128 keys), dbuf
    __shared__ alignas(16) short lP[4][32 * 72];  // per-wave P scratch, stride 72

    const int gid = blockIdx.x;
    const int h  = gid & 7;            // gid%8 -> XCD heuristic for K/V L2 locality
    int b        = (gid >> 3) & 3;
    const int qt = gid >> 5;           // 0..15, 128 rows per block
    b ^= 3 * ((gid >> 8) & 1);         // pair (b, b^3) batches on each CU: vlen balance
    const int w = threadIdx.x >> 6, lane = threadIdx.x & 63;
    const int l = lane & 15, qd = lane >> 4;
    const int vlen = valid_lens[b];
    const int nt2 = (vlen + 127) >> 7; // 128-key iterations; masked tail exact (exp2->0)

    const int bh = b * 8 + h;
    const short* Kf = kfrag + (size_t)bh * 32 * 4096;
    const short* Vf = vfrag + (size_t)bh * 32 * 4096;

    const int s0 = qt * 128 + w * 32;
    const f4v fz = {0.f, 0.f, 0.f, 0.f};
    const float SC = 0.125f * 1.442695041f;   // softmax scale * log2(e), folded into Q

    short* lPw = lP[w];
    const int toff = threadIdx.x * 8;  // 16B per thread; 4KB per gload round

    // ---- prologue 1: issue K tile-0 staging (flies under Q-projection) ----
#pragma unroll
    for (int r = 0; r < 4; r++)
        gload16(Kf + r * 2048 + toff, &kbuf[0][r * 2048 + toff]);

    // ---- prologue 2: Q-projection for this block's 128 rows ----
    short* wsm = &kbuf[1][0];          // 8 KB Wq^T tile; kbuf[1] free until j=0 prefetch
    short* qsm = &lP[0][0];            // 16 KB Q tile; lP free until first softmax
    {
        const int d = threadIdx.x >> 2, c4 = threadIdx.x & 3;   // 16 cols per thread
        const float* src = Wq + d * 64 + c4 * 16;
        f4v x0 = *(const f4v*)(src);
        f4v x1 = *(const f4v*)(src + 4);
        f4v x2 = *(const f4v*)(src + 8);
        f4v x3 = *(const f4v*)(src + 12);
        float xs[16] = {x0[0],x0[1],x0[2],x0[3], x1[0],x1[1],x1[2],x1[3],
                        x2[0],x2[1],x2[2],x2[3], x3[0],x3[1],x3[2],x3[3]};
#pragma unroll
        for (int j = 0; j < 16; j++) {
            int e = c4 * 16 + j;
            int sidx = (e * 64 + d) ^ (((e >> 2) & 7) << 3);
            wsm[sidx] = f2bf(xs[j]);
        }
    }
    __syncthreads();   // wsm visible (drains K tile-0 gloads too)

    {
        s8v a[2][2];
#pragma unroll
        for (int mt = 0; mt < 2; mt++)
#pragma unroll
            for (int kk = 0; kk < 2; kk++) {
                const float* p = q + (size_t)(b * S_LEN + s0 + mt * 16 + l) * 512 + h * 64 + kk * 32 + qd * 8;
                f4v x0 = *(const f4v*)p;
                f4v x1 = *(const f4v*)(p + 4);
                s8v fr;
                fr[0] = f2bf(x0[0]); fr[1] = f2bf(x0[1]); fr[2] = f2bf(x0[2]); fr[3] = f2bf(x0[3]);
                fr[4] = f2bf(x1[0]); fr[5] = f2bf(x1[1]); fr[6] = f2bf(x1[2]); fr[7] = f2bf(x1[3]);
                a[mt][kk] = fr;
            }
        s8v wf2[4][2];
#pragma unroll
        for (int nt = 0; nt < 4; nt++) {
            int wrow = 4 * l + nt;
            int key = ((wrow >> 2) & 7) << 3;
#pragma unroll
            for (int kk = 0; kk < 2; kk++)
                wf2[nt][kk] = *(const s8v*)(wsm + ((wrow * 64 + kk * 32 + qd * 8) ^ key));
        }
        f4v qacc[2][4];
#pragma unroll
        for (int mt = 0; mt < 2; mt++)
#pragma unroll
            for (int nt = 0; nt < 4; nt++) qacc[mt][nt] = fz;
#pragma unroll
        for (int kk = 0; kk < 2; kk++)
#pragma unroll
            for (int nt = 0; nt < 4; nt++)
#pragma unroll
                for (int mt = 0; mt < 2; mt++)
                    qacc[mt][nt] = MFMA(a[mt][kk], wf2[nt][kk], qacc[mt][nt], 0, 0, 0);

        float bbs[4];
#pragma unroll
        for (int nt = 0; nt < 4; nt++) bbs[nt] = bq[4 * l + nt];
#pragma unroll
        for (int mt = 0; mt < 2; mt++)
#pragma unroll
            for (int r = 0; r < 4; r++) {
                int sl = w * 32 + mt * 16 + qd * 4 + r;
                s4v pk;
#pragma unroll
                for (int nt = 0; nt < 4; nt++)
                    pk[nt] = f2bf((qacc[mt][nt][r] + bbs[nt]) * SC);
                int sidx = (sl * 64 + 4 * l) ^ (((sl >> 2) & 7) << 3);
                *(s4v*)(qsm + sidx) = pk;
            }
    }
    __syncthreads();   // qsm visible; wsm dead

    s8v qf[2][2];
#pragma unroll
    for (int mt = 0; mt < 2; mt++) {
        int sl = w * 32 + mt * 16 + l;
        int key = ((sl >> 2) & 7) << 3;
#pragma unroll
        for (int kk = 0; kk < 2; kk++)
            qf[mt][kk] = *(const s8v*)(qsm + ((sl * 64 + kk * 32 + qd * 8) ^ key));
    }
    __syncthreads();   // qf reads done; lP free for softmax, kbuf[1] free for prefetch

    f4v O[2][4];
    float lsum[2][4];
#pragma unroll
    for (int mt = 0; mt < 2; mt++)
#pragma unroll
        for (int r = 0; r < 4; r++) lsum[mt][r] = 0.f;
#pragma unroll
    for (int mt = 0; mt < 2; mt++)
#pragma unroll
        for (int ne = 0; ne < 4; ne++) O[mt][ne] = fz;

    for (int j = 0; j < nt2; j++) {
        const int cur = j & 1;
        // issue next-128-key K prefetch FIRST so it flies under this iter's compute
        if (j + 1 < nt2) {
            const short* Ks = Kf + (size_t)(j + 1) * 8192;
#pragma unroll
            for (int r = 0; r < 4; r++)
                gload16(Ks + r * 2048 + toff, &kbuf[cur ^ 1][r * 2048 + toff]);
        }

        // two sequential 64-key halves, one barrier for both
#pragma unroll
        for (int st = 0; st < 2; st++) {
            const int kb = 2 * j + st;

            // V fragments straight from global (L2-resident, coalesced 1KB/instr);
            // issued first, consumed after softmax -> QK+softmax covers L2 latency.
            const short* Vb = Vf + (size_t)kb * 4096 + lane * 8;
            s8v vf[4][2];
#pragma unroll
            for (int ne = 0; ne < 4; ne++)
#pragma unroll
                for (int kk = 0; kk < 2; kk++)
                    vf[ne][kk] = *(const s8v*)(Vb + (ne * 2 + kk) * 512);

            // K fragments from LDS: contiguous 1KB per chunk, conflict-free
            const short* Kb = &kbuf[cur][st * 4096 + lane * 8];
            s8v kf[4][2];
#pragma unroll
            for (int nt = 0; nt < 4; nt++)
#pragma unroll
                for (int kk = 0; kk < 2; kk++)
                    kf[nt][kk] = *(const s8v*)(Kb + (nt * 2 + kk) * 512);

            f4v sf[2][4];
#pragma unroll
            for (int mt = 0; mt < 2; mt++)
#pragma unroll
                for (int nt = 0; nt < 4; nt++) sf[mt][nt] = fz;
            __builtin_amdgcn_s_setprio(1);
#pragma unroll
            for (int nt = 0; nt < 4; nt++)
#pragma unroll
                for (int mt = 0; mt < 2; mt++) {
                    sf[mt][nt] = MFMA(qf[mt][0], kf[nt][0], sf[mt][nt], 0, 0, 0);
                    sf[mt][nt] = MFMA(qf[mt][1], kf[nt][1], sf[mt][nt], 0, 0, 0);
                }
            __builtin_amdgcn_s_setprio(0);

            // boundary mask (key at (nt,l) = kb*64 + 4*l + nt); rem<=0 -> all masked
            if (j == nt2 - 1) {
                int rem = vlen - kb * 64;
                if (rem < 64) {
#pragma unroll
                    for (int nt = 0; nt < 4; nt++)
                        if (4 * l + nt >= rem) {
#pragma unroll
                            for (int mt = 0; mt < 2; mt++)
#pragma unroll
                                for (int r = 0; r < 4; r++) sf[mt][nt][r] = -1e30f;
                        }
                }
            }

            // softmax, no max subtraction; truncating bf16 pack; ds_write_b64/row-reg
#pragma unroll
            for (int mt = 0; mt < 2; mt++)
#pragma unroll
                for (int r = 0; r < 4; r++) {
                    float p0 = __builtin_amdgcn_exp2f(sf[mt][0][r]);
                    float p1 = __builtin_amdgcn_exp2f(sf[mt][1][r]);
                    float p2 = __builtin_amdgcn_exp2f(sf[mt][2][r]);
                    float p3 = __builtin_amdgcn_exp2f(sf[mt][3][r]);
                    lsum[mt][r] += (p0 + p1) + (p2 + p3);
                    i2v pk;
                    pk[0] = (int)pack_bf2_trunc(p0, p1);
                    pk[1] = (int)pack_bf2_trunc(p2, p3);
                    *(i2v*)(lPw + (mt * 16 + qd * 4 + r) * 72 + 4 * l) = pk;
                }

            // O += P V  (A-frags from wave-private LDS; in-wave lgkm ordering)
            s8v pa[2][2];
#pragma unroll
            for (int mt = 0; mt < 2; mt++)
#pragma unroll
                for (int kk = 0; kk < 2; kk++)
                    pa[mt][kk] = *(const s8v*)(lPw + (mt * 16 + l) * 72 + kk * 32 + qd * 8);
            __builtin_amdgcn_s_setprio(1);
#pragma unroll
            for (int ne = 0; ne < 4; ne++)
#pragma unroll
                for (int mt = 0; mt < 2; mt++) {
                    O[mt][ne] = MFMA(pa[mt][0], vf[ne][0], O[mt][ne], 0, 0, 0);
                    O[mt][ne] = MFMA(pa[mt][1], vf[ne][1], O[mt][ne], 0, 0, 0);
                }
            __builtin_amdgcn_s_setprio(0);
        }

        // all waves done reading kbuf[cur]; K prefetch into kbuf[cur^1] drained here
        __syncthreads();
    }

    // normalize + write ctx[b][s][h*64 + e] (bf16), packed 8B stores (e = 4*l+ne)
#pragma unroll
    for (int mt = 0; mt < 2; mt++)
#pragma unroll
        for (int r = 0; r < 4; r++) {
            float inv = 1.0f / rowsum16(lsum[mt][r]);
            int s = s0 + mt * 16 + qd * 4 + r;
            s4v pk;
#pragma unroll
            for (int ne = 0; ne < 4; ne++) pk[ne] = f2bf(O[mt][ne][r] * inv);
            *(s4v*)(ctx + ((size_t)(b * S_LEN + s)) * 512 + h * 64 + 4 * l) = pk;
        }
}

// ---------------- output projection v2: barrier-free K-loop, A direct from L2 ---------
// [8192,512] = ctx @ Wo + bo. ctx is L2-hot (8MB): A frags read DIRECTLY from
// global (16B/lane, unroll-by-2 register prefetch); only the Wo^T tile is in LDS
// (staged once, one barrier total). Waves run barrier-free through the K loop.
__global__ __launch_bounds__(256) void outproj_kernel(
    const short* __restrict__ ctx, const short* __restrict__ WoT,
    const float* __restrict__ bo, float* __restrict__ out)
{
    __shared__ short lB[64 * 520];   // Wo^T tile, padded stride (kills 1024B-stride alias)

    const int rb = blockIdx.x * 128;
    const int nb = blockIdx.y * 64;
    const int w = threadIdx.x >> 6, lane = threadIdx.x & 63;
    const int l = lane & 15, qd = lane >> 4;

    {   // stage B tile once: 64 rows x 512
        int n = threadIdx.x >> 2, c0 = threadIdx.x & 3;
#pragma unroll
        for (int i = 0; i < 16; i++) {
            int g = i * 4 + c0;  // 64 granules of 8 shorts
            i4v x = *(const i4v*)(WoT + (size_t)(nb + n) * 512 + g * 8);
            *(i4v*)(lB + n * 520 + g * 8) = x;
        }
    }
    __syncthreads();   // the only barrier in this kernel

    const f4v fz = {0.f, 0.f, 0.f, 0.f};
    f4v acc[2][4];
#pragma unroll
    for (int mt = 0; mt < 2; mt++)
#pragma unroll
        for (int nt = 0; nt < 4; nt++) acc[mt][nt] = fz;

    // per-lane A base: row = rb + w*32 + mt*16 + l, col = ko*32 + qd*8
    const short* actx0 = ctx + (size_t)(rb + w * 32 + l) * 512 + qd * 8;
    const short* actx1 = actx0 + (size_t)16 * 512;

    s8v afA[2], afB[2];
    afA[0] = *(const s8v*)(actx0);
    afA[1] = *(const s8v*)(actx1);

#pragma unroll
    for (int ko = 0; ko < 16; ko += 2) {
        // prefetch ko+1 while computing ko
        afB[0] = *(const s8v*)(actx0 + (ko + 1) * 32);
        afB[1] = *(const s8v*)(actx1 + (ko + 1) * 32);
#pragma unroll
        for (int nt = 0; nt < 4; nt++) {
            s8v bfr = *(const s8v*)(lB + (nt * 16 + l) * 520 + ko * 32 + qd * 8);
#pragma unroll
            for (int mt = 0; mt < 2; mt++)
                acc[mt][nt] = MFMA(afA[mt], bfr, acc[mt][nt], 0, 0, 0);
        }
        if (ko + 2 < 16) {   // prefetch ko+2 while computing ko+1
            afA[0] = *(const s8v*)(actx0 + (ko + 2) * 32);
            afA[1] = *(const s8v*)(actx1 + (ko + 2) * 32);
        }
#pragma unroll
        for (int nt = 0; nt < 4; nt++) {
            s8v bfr = *(const s8v*)(lB + (nt * 16 + l) * 520 + (ko + 1) * 32 + qd * 8);
#pragma unroll
            for (int mt = 0; mt < 2; mt++)
                acc[mt][nt] = MFMA(afB[mt], bfr, acc[mt][nt], 0, 0, 0);
        }
    }

#pragma unroll
    for (int nt = 0; nt < 4; nt++) {
        float bias = bo[nb + nt * 16 + l];
#pragma unroll
        for (int mt = 0; mt < 2; mt++)
#pragma unroll
            for (int r = 0; r < 4; r++) {
                int row = rb + w * 32 + mt * 16 + qd * 4 + r;
                out[(size_t)row * 512 + nb + nt * 16 + l] = acc[mt][nt][r] + bias;
            }
    }
}

extern "C" void kernel_launch(void* const* d_in, const int* in_sizes, int n_in,
                              void* d_out, int out_size, void* d_ws, size_t ws_size,
                              hipStream_t stream)
{
    const float* q  = (const float*)d_in[0];
    const float* k  = (const float*)d_in[1];
    const float* v  = (const float*)d_in[2];
    const float* Wq = (const float*)d_in[3];
    const float* bq = (const float*)d_in[4];
    const float* Wk = (const float*)d_in[5];
    const float* bk = (const float*)d_in[6];
    const float* Wv = (const float*)d_in[7];
    const float* bv = (const float*)d_in[8];
    const float* Wo = (const float*)d_in[9];
    const float* bo = (const float*)d_in[10];
    const int*   vl = (const int*)d_in[11];
    float* out = (float*)d_out;

    char* ws = (char*)d_ws;
    const size_t SL = (size_t)4 * 8 * S_LEN * 64 * sizeof(short);  // 8 MiB per tensor
    short* ctx   = (short*)(ws);            // attn -> outproj
    short* kfrag = (short*)(ws + SL);       // proj -> attn
    short* vfrag = (short*)(ws + 2 * SL);   // proj -> attn
    short* WoT   = (short*)(ws + 3 * SL);   // prep -> outproj

    prep_kernel<<<64, 256, 0, stream>>>(Wo, WoT);
    proj_kernel<<<dim3(16, 8, 8), 256, 0, stream>>>(k, v, Wk, Wv, bk, bv, kfrag, vfrag);
    attn_kernel<<<512, 256, 0, stream>>>(q, Wq, bq, kfrag, vfrag, vl, ctx);
    outproj_kernel<<<dim3(64, 8), 256, 0, stream>>>(ctx, WoT, bo, out);
}

// Round 15
// 160.680 us; speedup vs baseline: 1.1532x; 1.0334x over previous
//
#include <hip/hip_runtime.h>

#define S_LEN 2048
#define D_MODEL 512

typedef __attribute__((ext_vector_type(8))) short s8v;   // 8 x bf16 (4 VGPRs) MFMA A/B frag
typedef __attribute__((ext_vector_type(4))) float f4v;   // MFMA C/D frag
typedef __attribute__((ext_vector_type(4))) short s4v;
typedef __attribute__((ext_vector_type(4))) int   i4v;
typedef __attribute__((ext_vector_type(2))) int   i2v;

#define MFMA __builtin_amdgcn_mfma_f32_16x16x32_bf16

__device__ inline short f2bf(float x) {            // fp32 -> bf16 RNE
    union { float f; unsigned u; } v; v.f = x;
    unsigned r = v.u + 0x7fffu + ((v.u >> 16) & 1u);
    return (short)(r >> 16);
}
__device__ inline unsigned pack_bf2_trunc(float a, float b) { // truncating pack: 3 inst
    unsigned ua = __builtin_bit_cast(unsigned, a);
    unsigned ub = __builtin_bit_cast(unsigned, b);
    return (ua >> 16) | (ub & 0xffff0000u);
}

template <int C>
__device__ inline float dppf(float x) {            // DPP permute within 16-lane row
    int i = __builtin_bit_cast(int, x);
    i = __builtin_amdgcn_update_dpp(0, i, C, 0xF, 0xF, true);
    return __builtin_bit_cast(float, i);
}
__device__ inline float rowsum16(float x) {
    x += dppf<0xB1>(x);
    x += dppf<0x4E>(x);
    x += dppf<0x141>(x);
    x += dppf<0x140>(x);
    return x;
}

// async global->LDS, 16B per lane. LDS dest is wave-uniform base + lane*16
// (per-lane pointers computed as base + tid*16 satisfy this layout).
typedef const __attribute__((address_space(1))) void* gptr_t;
typedef __attribute__((address_space(3))) void* sptr_t;
__device__ inline void gload16(const void* g, void* s) {
    __builtin_amdgcn_global_load_lds((gptr_t)g, (sptr_t)s, 16, 0, 0);
}

// ---------------- prep: Wo transpose to bf16 (LDS-tiled, coalesced) ----------------
__global__ __launch_bounds__(256) void prep_kernel(
    const float* __restrict__ Wo, short* __restrict__ WoT)
{
    __shared__ short t[64 * 65];
    const int bi = (blockIdx.x >> 3) * 64;   // input-dim base (i)
    const int bj = (blockIdx.x & 7) * 64;    // output-dim base (o)
    const int c = threadIdx.x & 63, rr = threadIdx.x >> 6;
#pragma unroll
    for (int r = 0; r < 16; r++) {
        int i = r * 4 + rr;
        t[c * 65 + i] = f2bf(Wo[(size_t)(bi + i) * 512 + bj + c]);  // coalesced read
    }
    __syncthreads();
#pragma unroll
    for (int r = 0; r < 16; r++) {
        int o = r * 4 + rr;
        WoT[(size_t)(bj + o) * 512 + bi + c] = t[o * 65 + c];       // coalesced write
    }
}

// ---------------- fused K/V projections+repack: kfrag/vfrag tiles ---------------------
// K/V only (Q lives in attn). NEW: vlen early-exit -- attn only reads frag tiles
// with qt*128 < vlen[b], so blocks beyond that exit immediately. E[kept] ~ 8.5/16
// -> ~47% of K/V projection work and ~16MB of fp32 k/v HBM reads eliminated.
__global__ __launch_bounds__(256) void proj_kernel(
    const float* __restrict__ k, const float* __restrict__ v,
    const float* __restrict__ Wk, const float* __restrict__ Wv,
    const float* __restrict__ bk, const float* __restrict__ bv,
    const int* __restrict__ valid_lens,
    short* __restrict__ kfrag, short* __restrict__ vfrag)
{
    __shared__ short sm[128 * 64];     // 16 KB union: wsm[64][64] -> ksm[128][64]/vsm[64][128]

    const int t2 = blockIdx.z >> 2;    // 0:k 1:v
    const int b = blockIdx.z & 3;
    const int h = blockIdx.y;
    const int qt = blockIdx.x;         // 16 row-tiles of 128
    if (qt * 128 >= valid_lens[b]) return;   // tile never read by attn

    const int w = threadIdx.x >> 6, lane = threadIdx.x & 63;
    const int l = lane & 15, qd = lane >> 4;

    const float* X    = (t2 == 0) ? k  : v;
    const float* Wp   = (t2 == 0) ? Wk : Wv;
    const float* bias = (t2 == 0) ? bk : bv;

    // ---- stage wsm[e][d] = W[d][e] (bf16, row-swizzled) ----
    {
        const int d = threadIdx.x >> 2, c4 = threadIdx.x & 3;   // 16 cols per thread
        const float* src = Wp + d * 64 + c4 * 16;
        f4v x0 = *(const f4v*)(src);
        f4v x1 = *(const f4v*)(src + 4);
        f4v x2 = *(const f4v*)(src + 8);
        f4v x3 = *(const f4v*)(src + 12);
        float xs[16] = {x0[0],x0[1],x0[2],x0[3], x1[0],x1[1],x1[2],x1[3],
                        x2[0],x2[1],x2[2],x2[3], x3[0],x3[1],x3[2],x3[3]};
#pragma unroll
        for (int j = 0; j < 16; j++) {
            int e = c4 * 16 + j;
            int sidx = (e * 64 + d) ^ (((e >> 2) & 7) << 3);
            sm[sidx] = f2bf(xs[j]);
        }
    }
    __syncthreads();

    const int s0 = qt * 128 + w * 32;

    // A frags direct from global fp32, converted
    s8v a[2][2];
#pragma unroll
    for (int mt = 0; mt < 2; mt++)
#pragma unroll
        for (int kk = 0; kk < 2; kk++) {
            const float* p = X + (size_t)(b * S_LEN + s0 + mt * 16 + l) * 512 + h * 64 + kk * 32 + qd * 8;
            f4v x0 = *(const f4v*)p;
            f4v x1 = *(const f4v*)(p + 4);
            s8v fr;
            fr[0] = f2bf(x0[0]); fr[1] = f2bf(x0[1]); fr[2] = f2bf(x0[2]); fr[3] = f2bf(x0[3]);
            fr[4] = f2bf(x1[0]); fr[5] = f2bf(x1[1]); fr[6] = f2bf(x1[2]); fr[7] = f2bf(x1[3]);
            a[mt][kk] = fr;
        }
    // B frags: k uses e = 4*l + nt, v uses e = nt*16 + l
    s8v wf[4][2];
#pragma unroll
    for (int nt = 0; nt < 4; nt++) {
        int wrow = (t2 == 0) ? (4 * l + nt) : (nt * 16 + l);
        int key = ((wrow >> 2) & 7) << 3;
#pragma unroll
        for (int kk = 0; kk < 2; kk++)
            wf[nt][kk] = *(const s8v*)(sm + ((wrow * 64 + kk * 32 + qd * 8) ^ key));
    }

    const f4v fz = {0.f, 0.f, 0.f, 0.f};
    f4v acc[2][4];
#pragma unroll
    for (int mt = 0; mt < 2; mt++)
#pragma unroll
        for (int nt = 0; nt < 4; nt++) acc[mt][nt] = fz;

#pragma unroll
    for (int kk = 0; kk < 2; kk++)
#pragma unroll
        for (int nt = 0; nt < 4; nt++)
#pragma unroll
            for (int mt = 0; mt < 2; mt++)
                acc[mt][nt] = MFMA(a[mt][kk], wf[nt][kk], acc[mt][nt], 0, 0, 0);

    __syncthreads();   // all wf reads done before sm is overwritten

    if (t2 == 0) {
        // ksm[s_local][e], stride 64, swizzle key (s_local>>2)&7
        float bbs[4];
#pragma unroll
        for (int nt = 0; nt < 4; nt++) bbs[nt] = bias[4 * l + nt];
#pragma unroll
        for (int mt = 0; mt < 2; mt++)
#pragma unroll
            for (int r = 0; r < 4; r++) {
                int sl = w * 32 + mt * 16 + qd * 4 + r;
                s4v pk;
#pragma unroll
                for (int nt = 0; nt < 4; nt++) pk[nt] = f2bf(acc[mt][nt][r] + bbs[nt]);
                int sidx = (sl * 64 + 4 * l) ^ (((sl >> 2) & 7) << 3);
                *(s4v*)(sm + sidx) = pk;
            }
    } else {
        // vsm[e][s_local], stride 128, swizzle key (e>>2)&7
#pragma unroll
        for (int nt = 0; nt < 4; nt++) {
            float bb = bias[nt * 16 + l];
            int e = nt * 16 + l;
            int key = ((e >> 2) & 7) << 3;
#pragma unroll
            for (int mt = 0; mt < 2; mt++) {
                s4v pk;
#pragma unroll
                for (int r = 0; r < 4; r++) pk[r] = f2bf(acc[mt][nt][r] + bb);
                int sidx = (e * 128 + w * 32 + mt * 16 + qd * 4) ^ key;
                *(s4v*)(sm + sidx) = pk;
            }
        }
    }
    __syncthreads();

    // ---- frag-order gather + coalesced stores (2 tiles x 8 chunks x 1KB) ----
    short* dst = (t2 == 0) ? kfrag : vfrag;
    const size_t obase0 = ((size_t)(b * 8 + h) * 32 + qt * 2) * 4096;
    const int f = threadIdx.x & 63, cp = threadIdx.x >> 6;
    const int fl = f & 15, fq = f >> 4;
#pragma unroll
    for (int tt = 0; tt < 2; tt++)
#pragma unroll
        for (int ci = 0; ci < 2; ci++) {
            int c = cp + ci * 4;
            int n2 = c >> 1, kk = c & 1;
            int sidx;
            if (t2 == 0) {
                int sl = tt * 64 + 4 * fl + n2;
                sidx = (sl * 64 + kk * 32 + fq * 8) ^ (((sl >> 2) & 7) << 3);
            } else {
                int e = 4 * fl + n2;
                sidx = (e * 128 + tt * 64 + kk * 32 + fq * 8) ^ (((e >> 2) & 7) << 3);
            }
            s8v x = *(const s8v*)(sm + sidx);
            *(s8v*)(dst + obase0 + tt * 4096 + c * 512 + f * 8) = x;
        }
}

// ---------------- flash attention v16: fused Q-proj + v12 loop + empty-half skip ------
// Prologue projects this block's 128 q-rows (wsm in kbuf[1], Q-tile via lP alias,
// overlapped with async K tile-0 staging). Loop = v12 (KVBLK=128, one barrier per
// 128 keys, K LDS dbuf, V direct from L2, b^3 pairing, setprio). NEW: a 64-key
// half fully beyond vlen contributes exactly 0 (all p = exp2(-1e30) = 0), so its
// whole body is skipped (block-uniform branch, no barrier inside).
__global__ __launch_bounds__(256, 2) void attn_kernel(
    const float* __restrict__ q, const float* __restrict__ Wq, const float* __restrict__ bq,
    const short* __restrict__ kfrag, const short* __restrict__ vfrag,
    const int* __restrict__ valid_lens, short* __restrict__ ctx)
{
    __shared__ alignas(16) short kbuf[2][8192];   // 16 KB K tile (128 keys), dbuf
    __shared__ alignas(16) short lP[4][32 * 72];  // per-wave P scratch, stride 72

    const int gid = blockIdx.x;
    const int h  = gid & 7;            // gid%8 -> XCD heuristic for K/V L2 locality
    int b        = (gid >> 3) & 3;
    const int qt = gid >> 5;           // 0..15, 128 rows per block
    b ^= 3 * ((gid >> 8) & 1);         // pair (b, b^3) batches on each CU: vlen balance
    const int w = threadIdx.x >> 6, lane = threadIdx.x & 63;
    const int l = lane & 15, qd = lane >> 4;
    const int vlen = valid_lens[b];
    const int nt2 = (vlen + 127) >> 7; // 128-key iterations; masked tail exact (exp2->0)

    const int bh = b * 8 + h;
    const short* Kf = kfrag + (size_t)bh * 32 * 4096;
    const short* Vf = vfrag + (size_t)bh * 32 * 4096;

    const int s0 = qt * 128 + w * 32;
    const f4v fz = {0.f, 0.f, 0.f, 0.f};
    const float SC = 0.125f * 1.442695041f;   // softmax scale * log2(e), folded into Q

    short* lPw = lP[w];
    const int toff = threadIdx.x * 8;  // 16B per thread; 4KB per gload round

    // ---- prologue 1: issue K tile-0 staging (flies under Q-projection) ----
#pragma unroll
    for (int r = 0; r < 4; r++)
        gload16(Kf + r * 2048 + toff, &kbuf[0][r * 2048 + toff]);

    // ---- prologue 2: Q-projection for this block's 128 rows ----
    short* wsm = &kbuf[1][0];          // 8 KB Wq^T tile; kbuf[1] free until j=0 prefetch
    short* qsm = &lP[0][0];            // 16 KB Q tile; lP free until first softmax
    {
        const int d = threadIdx.x >> 2, c4 = threadIdx.x & 3;   // 16 cols per thread
        const float* src = Wq + d * 64 + c4 * 16;
        f4v x0 = *(const f4v*)(src);
        f4v x1 = *(const f4v*)(src + 4);
        f4v x2 = *(const f4v*)(src + 8);
        f4v x3 = *(const f4v*)(src + 12);
        float xs[16] = {x0[0],x0[1],x0[2],x0[3], x1[0],x1[1],x1[2],x1[3],
                        x2[0],x2[1],x2[2],x2[3], x3[0],x3[1],x3[2],x3[3]};
#pragma unroll
        for (int j = 0; j < 16; j++) {
            int e = c4 * 16 + j;
            int sidx = (e * 64 + d) ^ (((e >> 2) & 7) << 3);
            wsm[sidx] = f2bf(xs[j]);
        }
    }
    __syncthreads();   // wsm visible (drains K tile-0 gloads too)

    {
        s8v a[2][2];
#pragma unroll
        for (int mt = 0; mt < 2; mt++)
#pragma unroll
            for (int kk = 0; kk < 2; kk++) {
                const float* p = q + (size_t)(b * S_LEN + s0 + mt * 16 + l) * 512 + h * 64 + kk * 32 + qd * 8;
                f4v x0 = *(const f4v*)p;
                f4v x1 = *(const f4v*)(p + 4);
                s8v fr;
                fr[0] = f2bf(x0[0]); fr[1] = f2bf(x0[1]); fr[2] = f2bf(x0[2]); fr[3] = f2bf(x0[3]);
                fr[4] = f2bf(x1[0]); fr[5] = f2bf(x1[1]); fr[6] = f2bf(x1[2]); fr[7] = f2bf(x1[3]);
                a[mt][kk] = fr;
            }
        s8v wf2[4][2];
#pragma unroll
        for (int nt = 0; nt < 4; nt++) {
            int wrow = 4 * l + nt;
            int key = ((wrow >> 2) & 7) << 3;
#pragma unroll
            for (int kk = 0; kk < 2; kk++)
                wf2[nt][kk] = *(const s8v*)(wsm + ((wrow * 64 + kk * 32 + qd * 8) ^ key));
        }
        f4v qacc[2][4];
#pragma unroll
        for (int mt = 0; mt < 2; mt++)
#pragma unroll
            for (int nt = 0; nt < 4; nt++) qacc[mt][nt] = fz;
#pragma unroll
        for (int kk = 0; kk < 2; kk++)
#pragma unroll
            for (int nt = 0; nt < 4; nt++)
#pragma unroll
                for (int mt = 0; mt < 2; mt++)
                    qacc[mt][nt] = MFMA(a[mt][kk], wf2[nt][kk], qacc[mt][nt], 0, 0, 0);

        float bbs[4];
#pragma unroll
        for (int nt = 0; nt < 4; nt++) bbs[nt] = bq[4 * l + nt];
#pragma unroll
        for (int mt = 0; mt < 2; mt++)
#pragma unroll
            for (int r = 0; r < 4; r++) {
                int sl = w * 32 + mt * 16 + qd * 4 + r;
                s4v pk;
#pragma unroll
                for (int nt = 0; nt < 4; nt++)
                    pk[nt] = f2bf((qacc[mt][nt][r] + bbs[nt]) * SC);
                int sidx = (sl * 64 + 4 * l) ^ (((sl >> 2) & 7) << 3);
                *(s4v*)(qsm + sidx) = pk;
            }
    }
    __syncthreads();   // qsm visible; wsm dead

    s8v qf[2][2];
#pragma unroll
    for (int mt = 0; mt < 2; mt++) {
        int sl = w * 32 + mt * 16 + l;
        int key = ((sl >> 2) & 7) << 3;
#pragma unroll
        for (int kk = 0; kk < 2; kk++)
            qf[mt][kk] = *(const s8v*)(qsm + ((sl * 64 + kk * 32 + qd * 8) ^ key));
    }
    __syncthreads();   // qf reads done; lP free for softmax, kbuf[1] free for prefetch

    f4v O[2][4];
    float lsum[2][4];
#pragma unroll
    for (int mt = 0; mt < 2; mt++)
#pragma unroll
        for (int r = 0; r < 4; r++) lsum[mt][r] = 0.f;
#pragma unroll
    for (int mt = 0; mt < 2; mt++)
#pragma unroll
        for (int ne = 0; ne < 4; ne++) O[mt][ne] = fz;

    for (int j = 0; j < nt2; j++) {
        const int cur = j & 1;
        // issue next-128-key K prefetch FIRST so it flies under this iter's compute
        if (j + 1 < nt2) {
            const short* Ks = Kf + (size_t)(j + 1) * 8192;
#pragma unroll
            for (int r = 0; r < 4; r++)
                gload16(Ks + r * 2048 + toff, &kbuf[cur ^ 1][r * 2048 + toff]);
        }

        // two sequential 64-key halves, one barrier for both
#pragma unroll
        for (int st = 0; st < 2; st++) {
            const int kb = 2 * j + st;
            if (kb * 64 >= vlen) continue;   // fully-masked half: contributes exactly 0

            // V fragments straight from global (L2-resident, coalesced 1KB/instr);
            // issued first, consumed after softmax -> QK+softmax covers L2 latency.
            const short* Vb = Vf + (size_t)kb * 4096 + lane * 8;
            s8v vf[4][2];
#pragma unroll
            for (int ne = 0; ne < 4; ne++)
#pragma unroll
                for (int kk = 0; kk < 2; kk++)
                    vf[ne][kk] = *(const s8v*)(Vb + (ne * 2 + kk) * 512);

            // K fragments from LDS: contiguous 1KB per chunk, conflict-free
            const short* Kb = &kbuf[cur][st * 4096 + lane * 8];
            s8v kf[4][2];
#pragma unroll
            for (int nt = 0; nt < 4; nt++)
#pragma unroll
                for (int kk = 0; kk < 2; kk++)
                    kf[nt][kk] = *(const s8v*)(Kb + (nt * 2 + kk) * 512);

            f4v sf[2][4];
#pragma unroll
            for (int mt = 0; mt < 2; mt++)
#pragma unroll
                for (int nt = 0; nt < 4; nt++) sf[mt][nt] = fz;
            __builtin_amdgcn_s_setprio(1);
#pragma unroll
            for (int nt = 0; nt < 4; nt++)
#pragma unroll
                for (int mt = 0; mt < 2; mt++) {
                    sf[mt][nt] = MFMA(qf[mt][0], kf[nt][0], sf[mt][nt], 0, 0, 0);
                    sf[mt][nt] = MFMA(qf[mt][1], kf[nt][1], sf[mt][nt], 0, 0, 0);
                }
            __builtin_amdgcn_s_setprio(0);

            // boundary mask (key at (nt,l) = kb*64 + 4*l + nt)
            {
                int rem = vlen - kb * 64;
                if (rem < 64) {
#pragma unroll
                    for (int nt = 0; nt < 4; nt++)
                        if (4 * l + nt >= rem) {
#pragma unroll
                            for (int mt = 0; mt < 2; mt++)
#pragma unroll
                                for (int r = 0; r < 4; r++) sf[mt][nt][r] = -1e30f;
                        }
                }
            }

            // softmax, no max subtraction; truncating bf16 pack; ds_write_b64/row-reg
#pragma unroll
            for (int mt = 0; mt < 2; mt++)
#pragma unroll
                for (int r = 0; r < 4; r++) {
                    float p0 = __builtin_amdgcn_exp2f(sf[mt][0][r]);
                    float p1 = __builtin_amdgcn_exp2f(sf[mt][1][r]);
                    float p2 = __builtin_amdgcn_exp2f(sf[mt][2][r]);
                    float p3 = __builtin_amdgcn_exp2f(sf[mt][3][r]);
                    lsum[mt][r] += (p0 + p1) + (p2 + p3);
                    i2v pk;
                    pk[0] = (int)pack_bf2_trunc(p0, p1);
                    pk[1] = (int)pack_bf2_trunc(p2, p3);
                    *(i2v*)(lPw + (mt * 16 + qd * 4 + r) * 72 + 4 * l) = pk;
                }

            // O += P V  (A-frags from wave-private LDS; in-wave lgkm ordering)
            s8v pa[2][2];
#pragma unroll
            for (int mt = 0; mt < 2; mt++)
#pragma unroll
                for (int kk = 0; kk < 2; kk++)
                    pa[mt][kk] = *(const s8v*)(lPw + (mt * 16 + l) * 72 + kk * 32 + qd * 8);
            __builtin_amdgcn_s_setprio(1);
#pragma unroll
            for (int ne = 0; ne < 4; ne++)
#pragma unroll
                for (int mt = 0; mt < 2; mt++) {
                    O[mt][ne] = MFMA(pa[mt][0], vf[ne][0], O[mt][ne], 0, 0, 0);
                    O[mt][ne] = MFMA(pa[mt][1], vf[ne][1], O[mt][ne], 0, 0, 0);
                }
            __builtin_amdgcn_s_setprio(0);
        }

        // all waves done reading kbuf[cur]; K prefetch into kbuf[cur^1] drained here
        __syncthreads();
    }

    // normalize + write ctx[b][s][h*64 + e] (bf16), packed 8B stores (e = 4*l+ne)
#pragma unroll
    for (int mt = 0; mt < 2; mt++)
#pragma unroll
        for (int r = 0; r < 4; r++) {
            float inv = 1.0f / rowsum16(lsum[mt][r]);
            int s = s0 + mt * 16 + qd * 4 + r;
            s4v pk;
#pragma unroll
            for (int ne = 0; ne < 4; ne++) pk[ne] = f2bf(O[mt][ne][r] * inv);
            *(s4v*)(ctx + ((size_t)(b * S_LEN + s)) * 512 + h * 64 + 4 * l) = pk;
        }
}

// ---------------- output projection v2: barrier-free K-loop, A direct from L2 ---------
// [8192,512] = ctx @ Wo + bo. ctx is L2-hot (8MB): A frags read DIRECTLY from
// global (16B/lane, unroll-by-2 register prefetch); only the Wo^T tile is in LDS
// (staged once, one barrier total). Waves run barrier-free through the K loop.
__global__ __launch_bounds__(256) void outproj_kernel(
    const short* __restrict__ ctx, const short* __restrict__ WoT,
    const float* __restrict__ bo, float* __restrict__ out)
{
    __shared__ short lB[64 * 520];   // Wo^T tile, padded stride (kills 1024B-stride alias)

    const int rb = blockIdx.x * 128;
    const int nb = blockIdx.y * 64;
    const int w = threadIdx.x >> 6, lane = threadIdx.x & 63;
    const int l = lane & 15, qd = lane >> 4;

    {   // stage B tile once: 64 rows x 512
        int n = threadIdx.x >> 2, c0 = threadIdx.x & 3;
#pragma unroll
        for (int i = 0; i < 16; i++) {
            int g = i * 4 + c0;  // 64 granules of 8 shorts
            i4v x = *(const i4v*)(WoT + (size_t)(nb + n) * 512 + g * 8);
            *(i4v*)(lB + n * 520 + g * 8) = x;
        }
    }
    __syncthreads();   // the only barrier in this kernel

    const f4v fz = {0.f, 0.f, 0.f, 0.f};
    f4v acc[2][4];
#pragma unroll
    for (int mt = 0; mt < 2; mt++)
#pragma unroll
        for (int nt = 0; nt < 4; nt++) acc[mt][nt] = fz;

    // per-lane A base: row = rb + w*32 + mt*16 + l, col = ko*32 + qd*8
    const short* actx0 = ctx + (size_t)(rb + w * 32 + l) * 512 + qd * 8;
    const short* actx1 = actx0 + (size_t)16 * 512;

    s8v afA[2], afB[2];
    afA[0] = *(const s8v*)(actx0);
    afA[1] = *(const s8v*)(actx1);

#pragma unroll
    for (int ko = 0; ko < 16; ko += 2) {
        // prefetch ko+1 while computing ko
        afB[0] = *(const s8v*)(actx0 + (ko + 1) * 32);
        afB[1] = *(const s8v*)(actx1 + (ko + 1) * 32);
#pragma unroll
        for (int nt = 0; nt < 4; nt++) {
            s8v bfr = *(const s8v*)(lB + (nt * 16 + l) * 520 + ko * 32 + qd * 8);
#pragma unroll
            for (int mt = 0; mt < 2; mt++)
                acc[mt][nt] = MFMA(afA[mt], bfr, acc[mt][nt], 0, 0, 0);
        }
        if (ko + 2 < 16) {   // prefetch ko+2 while computing ko+1
            afA[0] = *(const s8v*)(actx0 + (ko + 2) * 32);
            afA[1] = *(const s8v*)(actx1 + (ko + 2) * 32);
        }
#pragma unroll
        for (int nt = 0; nt < 4; nt++) {
            s8v bfr = *(const s8v*)(lB + (nt * 16 + l) * 520 + (ko + 1) * 32 + qd * 8);
#pragma unroll
            for (int mt = 0; mt < 2; mt++)
                acc[mt][nt] = MFMA(afB[mt], bfr, acc[mt][nt], 0, 0, 0);
        }
    }

#pragma unroll
    for (int nt = 0; nt < 4; nt++) {
        float bias = bo[nb + nt * 16 + l];
#pragma unroll
        for (int mt = 0; mt < 2; mt++)
#pragma unroll
            for (int r = 0; r < 4; r++) {
                int row = rb + w * 32 + mt * 16 + qd * 4 + r;
                out[(size_t)row * 512 + nb + nt * 16 + l] = acc[mt][nt][r] + bias;
            }
    }
}

extern "C" void kernel_launch(void* const* d_in, const int* in_sizes, int n_in,
                              void* d_out, int out_size, void* d_ws, size_t ws_size,
                              hipStream_t stream)
{
    const float* q  = (const float*)d_in[0];
    const float* k  = (const float*)d_in[1];
    const float* v  = (const float*)d_in[2];
    const float* Wq = (const float*)d_in[3];
    const float* bq = (const float*)d_in[4];
    const float* Wk = (const float*)d_in[5];
    const float* bk = (const float*)d_in[6];
    const float* Wv = (const float*)d_in[7];
    const float* bv = (const float*)d_in[8];
    const float* Wo = (const float*)d_in[9];
    const float* bo = (const float*)d_in[10];
    const int*   vl = (const int*)d_in[11];
    float* out = (float*)d_out;

    char* ws = (char*)d_ws;
    const size_t SL = (size_t)4 * 8 * S_LEN * 64 * sizeof(short);  // 8 MiB per tensor
    short* ctx   = (short*)(ws);            // attn -> outproj
    short* kfrag = (short*)(ws + SL);       // proj -> attn
    short* vfrag = (short*)(ws + 2 * SL);   // proj -> attn
    short* WoT   = (short*)(ws + 3 * SL);   // prep -> outproj

    prep_kernel<<<64, 256, 0, stream>>>(Wo, WoT);
    proj_kernel<<<dim3(16, 8, 8), 256, 0, stream>>>(k, v, Wk, Wv, bk, bv, vl,
                                                    kfrag, vfrag);
    attn_kernel<<<512, 256, 0, stream>>>(q, Wq, bq, kfrag, vfrag, vl, ctx);
    outproj_kernel<<<dim3(64, 8), 256, 0, stream>>>(ctx, WoT, bo, out);
}